// Round 14
// baseline (106.418 us; speedup 1.0000x reference)
//
#include <hip/hip_runtime.h>
#include <math.h>

#define N_ 4
#define T_ 8
#define C_ 512
#define H_ 14
#define W_ 14
#define HEADS_ 8
#define D_ 64
#define HW_ 196
#define S_ 1568
#define P_TOT 6272
#define KMP_ 1600        /* padded km row stride */
#define NEGL_ (-1.0e38f)
#define EPS_ 1e-8f
#define QSC_ 0.18033688011112042f   /* 0.125 * log2(e) */

typedef __attribute__((ext_vector_type(8))) short short8v;
typedef __attribute__((ext_vector_type(4))) float float4v;
typedef __attribute__((ext_vector_type(4))) unsigned short ushort4v;
typedef unsigned short ushort_t;

__device__ __forceinline__ ushort_t f2bf(float f) {
    union { float f; unsigned u; } a; a.f = f;
    unsigned r = (a.u + 0x7FFFu + ((a.u >> 16) & 1u)) >> 16;
    return (ushort_t)r;
}
__device__ __forceinline__ float bf2f(ushort_t u) {
    union { unsigned u; float f; } t; t.u = ((unsigned)u) << 16; return t.f;
}
__device__ __forceinline__ unsigned cvt_pk_bf16(float lo, float hi) {
    unsigned r;
    asm("v_cvt_pk_bf16_f32 %0, %1, %2" : "=v"(r) : "v"(lo), "v"(hi));
    return r;
}
__device__ __forceinline__ float exp2_fast(float x) {
    float r;
    asm("v_exp_f32 %0, %1" : "=v"(r) : "v"(x));
    return r;
}
__device__ __forceinline__ float max3f(float a, float b, float c) {
    float r;
    asm("v_max3_f32 %0, %1, %2, %3" : "=v"(r) : "v"(a), "v"(b), "v"(c));
    return r;
}
__device__ __forceinline__ float4v mfma16(short8v a, short8v b, float4v c) {
    return __builtin_amdgcn_mfma_f32_16x16x32_bf16(a, b, c, 0, 0, 0);
}
// Direct global -> LDS DMA. LDS dest = wave-uniform base + lane*size.
__device__ __forceinline__ void gload_lds16(const void* g, void* l) {
    __builtin_amdgcn_global_load_lds(
        (const __attribute__((address_space(1))) unsigned int*)g,
        (__attribute__((address_space(3))) unsigned int*)l,
        16, 0, 0);
}
__device__ __forceinline__ void gload_lds4(const void* g, void* l) {
    __builtin_amdgcn_global_load_lds(
        (const __attribute__((address_space(1))) unsigned int*)g,
        (__attribute__((address_space(3))) unsigned int*)l,
        4, 0, 0);
}

// ---------------------------------------------------------------------------
// Transpose pre-pass: (N,T,C,H,W) fp32 -> [p][c] bf16.  z==3: W fp32->bf16.
// ---------------------------------------------------------------------------
__global__ __launch_bounds__(256) void transpose_kernel(
    const float* __restrict__ q_in, const float* __restrict__ k_in,
    const float* __restrict__ v_in, ushort_t* __restrict__ qbf,
    ushort_t* __restrict__ kbf, ushort_t* __restrict__ vbf,
    const float* __restrict__ Wq, const float* __restrict__ Wk,
    const float* __restrict__ Wv, ushort_t* __restrict__ Wbf)
{
    __shared__ float Xs[64][197];
    const int z = blockIdx.z;
    const int nt = blockIdx.x;
    const int ct = blockIdx.y;
    const int tid = threadIdx.x;

    if (z == 3) {
        const int blk = nt * 8 + ct;
        #pragma unroll
        for (int i = 0; i < 3; ++i) {
            const int q = (blk * 3 + i) * 256 + tid;   // 0..196607
            const int zi = q >> 16;
            const int qi = q & 65535;
            const float* src = (zi == 0) ? Wq : (zi == 1) ? Wk : Wv;
            const float4 v = *(const float4*)(src + qi * 4);
            ushort4v pk;
            pk[0] = f2bf(v.x); pk[1] = f2bf(v.y);
            pk[2] = f2bf(v.z); pk[3] = f2bf(v.w);
            *(ushort4v*)(Wbf + (long)zi * 262144 + qi * 4) = pk;
        }
        return;
    }

    const float* src = (z == 0) ? q_in : (z == 1) ? k_in : v_in;
    ushort_t* dst = (z == 0) ? qbf : (z == 1) ? kbf : vbf;

    const long gbase = ((long)nt * C_ + ct * 64) * HW_;
    #pragma unroll
    for (int i = 0; i < 13; ++i) {
        const int idx = i * 256 + tid;          // 3136 float4 quads
        if (idx < 3136) {
            const int c = idx / 49;
            const int q4 = idx - c * 49;
            const float4 v = *(const float4*)(src + gbase + c * HW_ + q4 * 4);
            Xs[c][q4 * 4 + 0] = v.x;
            Xs[c][q4 * 4 + 1] = v.y;
            Xs[c][q4 * 4 + 2] = v.z;
            Xs[c][q4 * 4 + 3] = v.w;
        }
    }
    __syncthreads();
    const long pbase = (long)nt * HW_;
    const int c0 = (tid & 15) * 4;
    #pragma unroll
    for (int i = 0; i < 13; ++i) {
        const int idx = i * 256 + tid;
        if (idx < 3136) {
            const int hw = idx >> 4;
            ushort4v pk;
            #pragma unroll
            for (int e = 0; e < 4; ++e) pk[e] = f2bf(Xs[c0 + e][hw]);
            *(ushort4v*)(dst + (pbase + hw) * C_ + ct * 64 + c0) = pk;
        }
    }
}

// ---------------------------------------------------------------------------
// Padding masks. km stored as additive bias (0 / -1e38) in a PADDED [4][1600]
// layout (tail rows = -1e38). qm stays 1/0 at [n*S + s].
// ---------------------------------------------------------------------------
__global__ __launch_bounds__(256) void mask_kernel(
    const ushort_t* __restrict__ qbf, const ushort_t* __restrict__ kbf,
    float* __restrict__ qm, float* __restrict__ km)
{
    const int tid = threadIdx.x;
    const int w = tid >> 6, lane = tid & 63;
    const int p = blockIdx.x * 4 + w;
    const short8v qv = *(const short8v*)(qbf + (long)p * C_ + lane * 8);
    const short8v kv = *(const short8v*)(kbf + (long)p * C_ + lane * 8);
    float sq = 0.f, sk = 0.f;
    #pragma unroll
    for (int j = 0; j < 8; ++j) {
        sq += bf2f(((const ushort_t*)&qv)[j]);
        sk += bf2f(((const ushort_t*)&kv)[j]);
    }
    #pragma unroll
    for (int off = 32; off > 0; off >>= 1) {
        sq += __shfl_xor(sq, off, 64);
        sk += __shfl_xor(sk, off, 64);
    }
    if (lane == 0) {
        const int n = p / S_, s = p - n * S_;
        qm[p] = (sq != 0.f) ? 1.f : 0.f;
        km[n * KMP_ + s] = (sk != 0.f) ? 0.f : NEGL_;
    }
    if (blockIdx.x == 0 && tid < 128) {           // pad tail rows
        const int nn = tid >> 5;
        const int ss = S_ + (tid & 31);
        km[nn * KMP_ + ss] = NEGL_;
    }
}

// ---------------------------------------------------------------------------
// Projections: 1176 blocks (8 XCD chunks x 147), BM=128 p x BN=64 o (1 head).
// Double-buffered global_load_lds, ONE barrier per k-step (r13-verified).
// z=0 Q (pre-scaled by 0.125*log2e), z=1 K; z=2 V (out [b][d][s]).
// ---------------------------------------------------------------------------
__global__ __launch_bounds__(256) void proj_all(
    const ushort_t* __restrict__ qbf, const ushort_t* __restrict__ kbf,
    const ushort_t* __restrict__ vbf, const ushort_t* __restrict__ Wbf,
    const float* __restrict__ bq, const float* __restrict__ bk,
    const float* __restrict__ bv,
    ushort_t* __restrict__ Qh, ushort_t* __restrict__ Kh,
    ushort_t* __restrict__ Vt)
{
    __shared__ char lds[49152];   // 2 x (16KB X + 8KB W)

    const int fid = blockIdx.x;
    const int xcd = fid & 7;
    const int iin = fid >> 3;
    const int v = xcd * 147 + iin;           // 0..1175
    const int z = v / 392;                   // 392 = 49 ptiles x 8 heads
    const int rem = v - z * 392;
    const int ptile = rem >> 3;
    const int head = rem & 7;

    const ushort_t* Xbf = (z == 0) ? qbf : (z == 1) ? kbf : vbf;
    const ushort_t* Wz = Wbf + (long)z * 262144;
    const float* bias = (z == 0) ? bq : (z == 1) ? bk : bv;
    ushort_t* outp = (z == 0) ? Qh : (z == 1) ? Kh : Vt;
    const bool TR = (z == 2);
    const float osc = (z == 0) ? QSC_ : 1.0f;

    const int tid = threadIdx.x;
    const int w = tid >> 6, lane = tid & 63, lg = lane >> 4, lo = lane & 15;
    const int wr = w >> 1, wc = w & 1;
    const int p0 = ptile * 128;
    const int o0 = head * 64;

    const int wbase = (tid & 192) * 16;

    float4v acc[2][4];
    #pragma unroll
    for (int a = 0; a < 2; ++a)
        #pragma unroll
        for (int b = 0; b < 4; ++b) acc[a][b] = (float4v){0.f, 0.f, 0.f, 0.f};

    auto stage = [&](int buf, int k0) {
        char* Xl = lds + buf * 24576;
        char* Wl = Xl + 16384;
        #pragma unroll
        for (int i = 0; i < 4; ++i) {
            const int sl = tid + i * 256;
            const int row = sl >> 3, sir = sl & 7;
            const int c16 = sir ^ (row & 7);
            gload_lds16(Xbf + (long)(p0 + row) * C_ + k0 + c16 * 8,
                        Xl + i * 4096 + wbase);
        }
        #pragma unroll
        for (int i = 0; i < 2; ++i) {
            const int sl = tid + i * 256;
            const int row = sl >> 3, sir = sl & 7;
            const int c16 = sir ^ (row & 7);
            gload_lds16(Wz + (long)(o0 + row) * C_ + k0 + c16 * 8,
                        Wl + i * 4096 + wbase);
        }
    };

    stage(0, 0);
    #pragma unroll
    for (int kstep = 0; kstep < 8; ++kstep) {
        __syncthreads();
        if (kstep < 7) stage((kstep + 1) & 1, (kstep + 1) * 64);

        const char* Xl = lds + (kstep & 1) * 24576;
        const char* Wl = Xl + 16384;
        short8v wf[2][2], xf[4][2];
        #pragma unroll
        for (int a = 0; a < 2; ++a) {
            const int row = wc * 32 + a * 16 + lo;
            const int swr = (row & 7) << 4;
            #pragma unroll
            for (int ks = 0; ks < 2; ++ks) {
                const int base = row * 128 + ks * 64 + lg * 8;
                ((uint2*)&wf[a][ks])[0] = *(const uint2*)(Wl + (base ^ swr));
                ((uint2*)&wf[a][ks])[1] = *(const uint2*)(Wl + ((base + 32) ^ swr));
            }
        }
        #pragma unroll
        for (int b = 0; b < 4; ++b) {
            const int row = wr * 64 + b * 16 + lo;
            const int swr = (row & 7) << 4;
            #pragma unroll
            for (int ks = 0; ks < 2; ++ks) {
                const int base = row * 128 + ks * 64 + lg * 8;
                ((uint2*)&xf[b][ks])[0] = *(const uint2*)(Xl + (base ^ swr));
                ((uint2*)&xf[b][ks])[1] = *(const uint2*)(Xl + ((base + 32) ^ swr));
            }
        }
        __builtin_amdgcn_s_setprio(1);
        if (!TR) {
            #pragma unroll
            for (int ks = 0; ks < 2; ++ks)
                #pragma unroll
                for (int a = 0; a < 2; ++a)
                    #pragma unroll
                    for (int b = 0; b < 4; ++b)
                        acc[a][b] = mfma16(wf[a][ks], xf[b][ks], acc[a][b]);
        } else {
            #pragma unroll
            for (int ks = 0; ks < 2; ++ks)
                #pragma unroll
                for (int a = 0; a < 2; ++a)
                    #pragma unroll
                    for (int b = 0; b < 4; ++b)
                        acc[a][b] = mfma16(xf[b][ks], wf[a][ks], acc[a][b]);
        }
        __builtin_amdgcn_s_setprio(0);
    }

    if (!TR) {
        #pragma unroll
        for (int b = 0; b < 4; ++b) {
            const int p = p0 + wr * 64 + b * 16 + lo;
            const int nb = p / S_;
            const int s = p - nb * S_;
            #pragma unroll
            for (int a = 0; a < 2; ++a) {
                const int d0 = wc * 32 + a * 16 + lg * 4;
                const float4v bs = *(const float4v*)(bias + o0 + d0);
                ushort4v pk;
                #pragma unroll
                for (int e = 0; e < 4; ++e) {
                    float vv = acc[a][b][e] + bs[e];
                    vv = vv > 0.f ? vv : 0.f;
                    pk[e] = f2bf(vv * osc);
                }
                *(ushort4v*)(outp + ((long)(head * N_ + nb) * S_ + s) * D_ + d0) = pk;
            }
        }
    } else {
        #pragma unroll
        for (int a = 0; a < 2; ++a) {
            const int d = wc * 32 + a * 16 + lo;
            const float bsc = bias[o0 + d];
            #pragma unroll
            for (int b = 0; b < 4; ++b) {
                const int pb = p0 + wr * 64 + b * 16 + lg * 4;
                const int nb = pb / S_;
                const int s0 = pb - nb * S_;
                ushort4v pk;
                #pragma unroll
                for (int e = 0; e < 4; ++e) {
                    float vv = acc[a][b][e] + bsc;
                    vv = vv > 0.f ? vv : 0.f;
                    pk[e] = f2bf(vv);
                }
                *(ushort4v*)(outp + ((long)(head * N_ + nb) * D_ + d) * S_ + s0) = pk;
            }
        }
    }
}

// ---------------------------------------------------------------------------
// Split-K(x4) flash attention, QBLK=128 (2 q-groups per wave). Each staged
// K/V tile feeds both groups: kf/vf LDS reads amortized 2x, staging DMA per
// unit work halved. r10 staging structure (single buffer, 2 barriers/tile).
// Grid: 416 (32 b x 13 q-tiles, XCD-chunked) x 4 splits.
// ---------------------------------------------------------------------------
__global__ __launch_bounds__(256) void attn_kernel(
    const ushort_t* __restrict__ Qh, const ushort_t* __restrict__ Kh,
    const ushort_t* __restrict__ Vt, const float* __restrict__ km,
    ushort_t* __restrict__ Pc, float* __restrict__ Ml)
{
    __shared__ char lds[16384 + 256];   // K 8KB | V 8KB | kms 256B

    const int tid = threadIdx.x;
    const int lane = tid & 63;
    const int w = tid >> 6;
    const int lg = lane >> 4;
    const int lo = lane & 15;

    const int split = blockIdx.y;               // 0..3
    const int t1 = 7 + split * 6;               // 7,13,19,25
    const int t0 = split ? (1 + split * 6) : 0; // 0,7,13,19

    const int fid = blockIdx.x;          // 0..415, XCD-aware decode (416=8x52)
    const int x = fid & 7;
    const int j = fid >> 3;              // 0..51
    const int b = x + 8 * (j / 13);
    const int q0 = (j % 13) * 128;
    const int n = b & (N_ - 1);

    char* Kl = lds;
    char* Vl = lds + 8192;
    const float* kms = (const float*)(lds + 16384);
    const int wbase = (tid & 192) * 16;

    int qrow[2];
    short8v qf[2][2];
    #pragma unroll
    for (int g = 0; g < 2; ++g) {
        qrow[g] = q0 + g * 64 + w * 16 + lo;
        const int qcl = qrow[g] < S_ ? qrow[g] : S_ - 1;
        const ushort_t* qp = Qh + ((long)b * S_ + qcl) * D_ + lg * 4;
        #pragma unroll
        for (int ks = 0; ks < 2; ++ks) {
            ((uint2*)&qf[g][ks])[0] = *(const uint2*)(qp + ks * 32);
            ((uint2*)&qf[g][ks])[1] = *(const uint2*)(qp + ks * 32 + 16);
        }
    }

    float4v acc[2][4];
    #pragma unroll
    for (int g = 0; g < 2; ++g)
        #pragma unroll
        for (int dt = 0; dt < 4; ++dt) acc[g][dt] = (float4v){0.f, 0.f, 0.f, 0.f};
    float m_run[2] = {-INFINITY, -INFINITY};
    float l_run[2] = {0.f, 0.f};

    auto stage = [&](int kb) {
        #pragma unroll
        for (int i = 0; i < 2; ++i) {
            const int s = i * 256 + tid;
            const int row = s >> 3;
            const int c16 = (s & 7) ^ (row & 7);
            int krow = kb + row; if (krow >= S_) krow = S_ - 1;
            gload_lds16(Kh + ((long)b * S_ + krow) * D_ + c16 * 8,
                        Kl + i * 4096 + wbase);
        }
        #pragma unroll
        for (int i = 0; i < 2; ++i) {
            const int s = i * 256 + tid;
            const int row = s >> 3;
            const int c16 = (s & 7) ^ (row & 7);
            int kc = kb + c16 * 8; if (kc > S_ - 8) kc = S_ - 8;
            gload_lds16(Vt + ((long)b * D_ + row) * S_ + kc,
                        Vl + i * 4096 + wbase);
        }
        if (w == 0)
            gload_lds4(km + (long)n * KMP_ + kb + lane, (void*)kms);
    };

    for (int t = t0; t < t1; ++t) {
        stage(t * 64);
        __syncthreads();

        // ---- QK^T for both q-groups; kf shared ----
        float4v s[2][4];
        __builtin_amdgcn_s_setprio(1);
        #pragma unroll
        for (int kt = 0; kt < 4; ++kt) {
            #pragma unroll
            for (int g = 0; g < 2; ++g) s[g][kt] = (float4v){0.f, 0.f, 0.f, 0.f};
            const int row = kt * 16 + lo;
            const int base = row * 128 + lg * 8;
            const int swr = (row & 7) << 4;
            #pragma unroll
            for (int ks = 0; ks < 2; ++ks) {
                short8v kf;
                ((uint2*)&kf)[0] = *(const uint2*)(Kl + ((base + ks * 64) ^ swr));
                ((uint2*)&kf)[1] = *(const uint2*)(Kl + ((base + ks * 64 + 32) ^ swr));
                #pragma unroll
                for (int g = 0; g < 2; ++g)
                    s[g][kt] = mfma16(kf, qf[g][ks], s[g][kt]);
            }
        }
        __builtin_amdgcn_s_setprio(0);

        // ---- softmax per group (sequential so p[] lifetimes don't overlap) ----
        short8v pf[2][2];
        #pragma unroll
        for (int g = 0; g < 2; ++g) {
            float p[4][4];
            #pragma unroll
            for (int kt = 0; kt < 4; ++kt) {
                const float4v bv4 = *(const float4v*)&kms[kt * 16 + lg * 4];
                #pragma unroll
                for (int r = 0; r < 4; ++r) p[kt][r] = s[g][kt][r] + bv4[r];
            }
            const float m1 = max3f(p[0][0], p[0][1], p[0][2]);
            const float m2 = max3f(p[0][3], p[1][0], p[1][1]);
            const float m3 = max3f(p[1][2], p[1][3], p[2][0]);
            const float m4 = max3f(p[2][1], p[2][2], p[2][3]);
            const float m5 = max3f(p[3][0], p[3][1], p[3][2]);
            float mx = max3f(max3f(m1, m2, m3), m4, fmaxf(m5, p[3][3]));
            mx = fmaxf(mx, __shfl_xor(mx, 16, 64));
            mx = fmaxf(mx, __shfl_xor(mx, 32, 64));
            float mn;
            if (__all(mx <= m_run[g] + 8.f)) {
                mn = m_run[g];
            } else {
                mn = fmaxf(m_run[g], mx);
                const float alpha = exp2_fast(m_run[g] - mn);
                m_run[g] = mn;
                l_run[g] *= alpha;
                #pragma unroll
                for (int dt = 0; dt < 4; ++dt)
                    #pragma unroll
                    for (int r = 0; r < 4; ++r) acc[g][dt][r] *= alpha;
            }
            float rs4[4];
            #pragma unroll
            for (int kt = 0; kt < 4; ++kt) {
                #pragma unroll
                for (int r = 0; r < 4; ++r) p[kt][r] = exp2_fast(p[kt][r] - mn);
                rs4[kt] = (p[kt][0] + p[kt][1]) + (p[kt][2] + p[kt][3]);
            }
            l_run[g] += (rs4[0] + rs4[1]) + (rs4[2] + rs4[3]);

            #pragma unroll
            for (int kt = 0; kt < 4; ++kt) {
                const unsigned w0 = cvt_pk_bf16(p[kt][0], p[kt][1]);
                const unsigned w1 = cvt_pk_bf16(p[kt][2], p[kt][3]);
                ((unsigned*)&pf[g][kt >> 1])[(kt & 1) * 2] = w0;
                ((unsigned*)&pf[g][kt >> 1])[(kt & 1) * 2 + 1] = w1;
            }
        }

        // ---- PV for both q-groups; vf shared ----
        __builtin_amdgcn_s_setprio(1);
        #pragma unroll
        for (int dt = 0; dt < 4; ++dt) {
            const int row = dt * 16 + lo;
            const int base = row * 128 + lg * 8;
            const int swr = (row & 7) << 4;
            #pragma unroll
            for (int ks = 0; ks < 2; ++ks) {
                short8v vf;
                ((uint2*)&vf)[0] = *(const uint2*)(Vl + ((base + ks * 64) ^ swr));
                ((uint2*)&vf)[1] = *(const uint2*)(Vl + ((base + ks * 64 + 32) ^ swr));
                #pragma unroll
                for (int g = 0; g < 2; ++g)
                    acc[g][dt] = mfma16(vf, pf[g][ks], acc[g][dt]);
            }
        }
        __builtin_amdgcn_s_setprio(0);
        __syncthreads();
    }

    #pragma unroll
    for (int g = 0; g < 2; ++g) {
        l_run[g] += __shfl_xor(l_run[g], 16, 64);
        l_run[g] += __shfl_xor(l_run[g], 32, 64);
        if (qrow[g] < S_) {
            const long rbase = ((long)split * 32 + b) * S_ + qrow[g];
            if (lg == 0) {
                Ml[rbase * 2] = m_run[g];
                Ml[rbase * 2 + 1] = l_run[g];
            }
            ushort_t* P = Pc + rbase * 64;
            #pragma unroll
            for (int dt = 0; dt < 4; ++dt) {
                uint2 uu;
                uu.x = cvt_pk_bf16(acc[g][dt][0], acc[g][dt][1]);
                uu.y = cvt_pk_bf16(acc[g][dt][2], acc[g][dt][3]);
                *(uint2*)(P + dt * 16 + lg * 4) = uu;
            }
        }
    }
}

// ---------------------------------------------------------------------------
// Fused split-K combine (exp2-domain lse merge, qm, 1/l) + LN stats.
// ---------------------------------------------------------------------------
__global__ __launch_bounds__(256) void combine_stats_kernel(
    const ushort_t* __restrict__ Pc, const float* __restrict__ Ml,
    const float* __restrict__ qm, const ushort_t* __restrict__ qbf,
    ushort_t* __restrict__ Om, float* __restrict__ stats)
{
    const int tid = threadIdx.x;
    const int wv = tid >> 6, lane = tid & 63;
    const long pos = (long)blockIdx.x * 4 + wv;     // n*S + q
    const int n = (int)(pos / S_);
    const int q = (int)(pos - (long)n * S_);
    const int head = lane >> 3;
    const int d0 = (lane & 7) * 8;

    long rb[4];
    float mv[4], lv[4];
    float M = -INFINITY;
    #pragma unroll
    for (int s = 0; s < 4; ++s) {
        rb[s] = ((long)(s * 32 + head * 4 + n) * S_ + q);
        const float2 ml = *(const float2*)(Ml + rb[s] * 2);
        mv[s] = ml.x; lv[s] = ml.y;
        M = fmaxf(M, ml.x);
    }
    float L = 0.f;
    float o[8] = {0.f, 0.f, 0.f, 0.f, 0.f, 0.f, 0.f, 0.f};
    #pragma unroll
    for (int s = 0; s < 4; ++s) {
        const float wgt = exp2_fast(mv[s] - M);
        L = fmaf(lv[s], wgt, L);
        const ushort4v a0 = *(const ushort4v*)(Pc + rb[s] * 64 + d0);
        const ushort4v a1 = *(const ushort4v*)(Pc + rb[s] * 64 + d0 + 4);
        #pragma unroll
        for (int e = 0; e < 4; ++e) {
            o[e] = fmaf(bf2f(a0[e]), wgt, o[e]);
            o[4 + e] = fmaf(bf2f(a1[e]), wgt, o[4 + e]);
        }
    }
    L = fmaxf(L, 1e-20f);
    const float scale = qm[pos] / L;
    const short8v qv = *(const short8v*)(qbf + pos * C_ + lane * 8);
    ushort4v ov0, ov1;
    float sum = 0.f, ssq = 0.f;
    #pragma unroll
    for (int e = 0; e < 8; ++e) {
        const ushort_t ob = f2bf(o[e] * scale);
        if (e < 4) ov0[e] = ob; else ov1[e - 4] = ob;
        const float v = bf2f(ob) + bf2f(((const ushort_t*)&qv)[e]);
        sum += v; ssq += v * v;
    }
    #pragma unroll
    for (int off = 32; off > 0; off >>= 1) {
        sum += __shfl_xor(sum, off, 64);
        ssq += __shfl_xor(ssq, off, 64);
    }
    *(ushort4v*)(Om + pos * C_ + lane * 8) = ov0;
    *(ushort4v*)(Om + pos * C_ + lane * 8 + 4) = ov1;
    if (lane == 0) {
        const float mean = sum * (1.f / 512.f);
        float var = (ssq - sum * mean) * (1.f / 511.f);
        var = var > 0.f ? var : 0.f;
        stats[pos * 2] = mean;
        stats[pos * 2 + 1] = 1.f / (sqrtf(var) + EPS_);
    }
}

// ---------------------------------------------------------------------------
// LN pass 2: normalize + gamma/beta, LDS-transposed, float4 writes
// ---------------------------------------------------------------------------
__global__ __launch_bounds__(256) void ln_write_kernel(
    const ushort_t* __restrict__ Om, const ushort_t* __restrict__ qbf,
    const float* __restrict__ stats, const float* __restrict__ gamma,
    const float* __restrict__ beta, float* __restrict__ out)
{
    __shared__ float Tl[64][197];
    const int nt = blockIdx.x;
    const int ct = blockIdx.y;
    const int tid = threadIdx.x;

    const int c0 = (tid & 15) * 4;
    float g[4], bb[4];
    #pragma unroll
    for (int e = 0; e < 4; ++e) {
        g[e] = gamma[ct * 64 + c0 + e];
        bb[e] = beta[ct * 64 + c0 + e];
    }

    #pragma unroll
    for (int i = 0; i < 13; ++i) {
        const int idx = i * 256 + tid;
        if (idx < 3136) {
            const int hw = idx >> 4;
            const long p = (long)nt * HW_ + hw;
            const float mean = stats[p * 2];
            const float inv = stats[p * 2 + 1];
            const ushort4v ov = *(const ushort4v*)(Om + p * C_ + ct * 64 + c0);
            const ushort4v qv = *(const ushort4v*)(qbf + p * C_ + ct * 64 + c0);
            #pragma unroll
            for (int e = 0; e < 4; ++e) {
                const float xv = bf2f(ov[e]) + bf2f(qv[e]);
                Tl[c0 + e][hw] = g[e] * (xv - mean) * inv + bb[e];
            }
        }
    }
    __syncthreads();
    const long obase = ((long)nt * C_ + ct * 64) * HW_;
    #pragma unroll
    for (int i = 0; i < 13; ++i) {
        const int idx = i * 256 + tid;
        if (idx < 3136) {
            const int c = idx / 49;
            const int q4 = idx - c * 49;
            float4 v;
            v.x = Tl[c][q4 * 4 + 0];
            v.y = Tl[c][q4 * 4 + 1];
            v.z = Tl[c][q4 * 4 + 2];
            v.w = Tl[c][q4 * 4 + 3];
            *(float4*)(out + obase + c * HW_ + q4 * 4) = v;
        }
    }
}

extern "C" void kernel_launch(void* const* d_in, const int* in_sizes, int n_in,
                              void* d_out, int out_size, void* d_ws, size_t ws_size,
                              hipStream_t stream) {
    const float* q_in  = (const float*)d_in[0];
    const float* k_in  = (const float*)d_in[1];
    const float* v_in  = (const float*)d_in[2];
    const float* Wq    = (const float*)d_in[3];
    const float* bq    = (const float*)d_in[4];
    const float* Wk    = (const float*)d_in[5];
    const float* bk    = (const float*)d_in[6];
    const float* Wv    = (const float*)d_in[7];
    const float* bv    = (const float*)d_in[8];
    const float* gamma = (const float*)d_in[9];
    const float* beta  = (const float*)d_in[10];
    float* out = (float*)d_out;

    const size_t PC = (size_t)P_TOT * C_;            // 3,211,264
    ushort_t* qbf = (ushort_t*)d_ws;
    ushort_t* kbf = qbf + PC;
    ushort_t* vbf = kbf + PC;
    ushort_t* Wbf = vbf + PC;                        // 3 x 512 x 512 bf16
    ushort_t* Qh  = Wbf + 3 * (size_t)C_ * C_;
    ushort_t* Kh  = Qh + PC;
    ushort_t* Vt  = Kh + PC;
    ushort_t* Om  = Vt + PC;                         // bf16
    ushort_t* Pc  = Om + PC;                         // 4*32*1568*64 bf16
    float* Ml    = (float*)(Pc + 4L * 32 * S_ * 64);
    float* stats = Ml + 4L * 32 * S_ * 2;
    float* qm    = stats + 2 * P_TOT;
    float* km    = qm + P_TOT;                       // padded [4][1600]

    transpose_kernel<<<dim3(32, 8, 4), 256, 0, stream>>>(
        q_in, k_in, v_in, qbf, kbf, vbf, Wq, Wk, Wv, Wbf);
    mask_kernel<<<P_TOT / 4, 256, 0, stream>>>(qbf, kbf, qm, km);
    proj_all<<<1176, 256, 0, stream>>>(qbf, kbf, vbf, Wbf, bq, bk, bv, Qh, Kh, Vt);
    attn_kernel<<<dim3(416, 4), 256, 0, stream>>>(Qh, Kh, Vt, km, Pc, Ml);
    combine_stats_kernel<<<P_TOT / 4, 256, 0, stream>>>(Pc, Ml, qm, qbf, Om, stats);
    ln_write_kernel<<<dim3(32, 8), 256, 0, stream>>>(Om, qbf, stats, gamma, beta, out);
}

// Round 15
// 101.585 us; speedup vs baseline: 1.0476x; 1.0476x over previous
//
#include <hip/hip_runtime.h>
#include <math.h>

#define N_ 4
#define T_ 8
#define C_ 512
#define H_ 14
#define W_ 14
#define HEADS_ 8
#define D_ 64
#define HW_ 196
#define S_ 1568
#define P_TOT 6272
#define KMP_ 1600        /* padded km row stride */
#define NEGL_ (-1.0e38f)
#define EPS_ 1e-8f
#define QSC_ 0.18033688011112042f   /* 0.125 * log2(e) */

typedef __attribute__((ext_vector_type(8))) short short8v;
typedef __attribute__((ext_vector_type(4))) float float4v;
typedef __attribute__((ext_vector_type(4))) unsigned short ushort4v;
typedef unsigned short ushort_t;

__device__ __forceinline__ ushort_t f2bf(float f) {
    union { float f; unsigned u; } a; a.f = f;
    unsigned r = (a.u + 0x7FFFu + ((a.u >> 16) & 1u)) >> 16;
    return (ushort_t)r;
}
__device__ __forceinline__ float bf2f(ushort_t u) {
    union { unsigned u; float f; } t; t.u = ((unsigned)u) << 16; return t.f;
}
__device__ __forceinline__ unsigned cvt_pk_bf16(float lo, float hi) {
    unsigned r;
    asm("v_cvt_pk_bf16_f32 %0, %1, %2" : "=v"(r) : "v"(lo), "v"(hi));
    return r;
}
__device__ __forceinline__ float exp2_fast(float x) {
    float r;
    asm("v_exp_f32 %0, %1" : "=v"(r) : "v"(x));
    return r;
}
__device__ __forceinline__ float max3f(float a, float b, float c) {
    float r;
    asm("v_max3_f32 %0, %1, %2, %3" : "=v"(r) : "v"(a), "v"(b), "v"(c));
    return r;
}
__device__ __forceinline__ float4v mfma16(short8v a, short8v b, float4v c) {
    return __builtin_amdgcn_mfma_f32_16x16x32_bf16(a, b, c, 0, 0, 0);
}
// Direct global -> LDS DMA. LDS dest = wave-uniform base + lane*size.
__device__ __forceinline__ void gload_lds16(const void* g, void* l) {
    __builtin_amdgcn_global_load_lds(
        (const __attribute__((address_space(1))) unsigned int*)g,
        (__attribute__((address_space(3))) unsigned int*)l,
        16, 0, 0);
}
__device__ __forceinline__ void gload_lds4(const void* g, void* l) {
    __builtin_amdgcn_global_load_lds(
        (const __attribute__((address_space(1))) unsigned int*)g,
        (__attribute__((address_space(3))) unsigned int*)l,
        4, 0, 0);
}

// ---------------------------------------------------------------------------
// Transpose pre-pass: (N,T,C,H,W) fp32 -> [p][c] bf16.  z==3: W fp32->bf16.
// ---------------------------------------------------------------------------
__global__ __launch_bounds__(256) void transpose_kernel(
    const float* __restrict__ q_in, const float* __restrict__ k_in,
    const float* __restrict__ v_in, ushort_t* __restrict__ qbf,
    ushort_t* __restrict__ kbf, ushort_t* __restrict__ vbf,
    const float* __restrict__ Wq, const float* __restrict__ Wk,
    const float* __restrict__ Wv, ushort_t* __restrict__ Wbf)
{
    __shared__ float Xs[64][197];
    const int z = blockIdx.z;
    const int nt = blockIdx.x;
    const int ct = blockIdx.y;
    const int tid = threadIdx.x;

    if (z == 3) {
        const int blk = nt * 8 + ct;
        #pragma unroll
        for (int i = 0; i < 3; ++i) {
            const int q = (blk * 3 + i) * 256 + tid;   // 0..196607
            const int zi = q >> 16;
            const int qi = q & 65535;
            const float* src = (zi == 0) ? Wq : (zi == 1) ? Wk : Wv;
            const float4 v = *(const float4*)(src + qi * 4);
            ushort4v pk;
            pk[0] = f2bf(v.x); pk[1] = f2bf(v.y);
            pk[2] = f2bf(v.z); pk[3] = f2bf(v.w);
            *(ushort4v*)(Wbf + (long)zi * 262144 + qi * 4) = pk;
        }
        return;
    }

    const float* src = (z == 0) ? q_in : (z == 1) ? k_in : v_in;
    ushort_t* dst = (z == 0) ? qbf : (z == 1) ? kbf : vbf;

    const long gbase = ((long)nt * C_ + ct * 64) * HW_;
    #pragma unroll
    for (int i = 0; i < 13; ++i) {
        const int idx = i * 256 + tid;          // 3136 float4 quads
        if (idx < 3136) {
            const int c = idx / 49;
            const int q4 = idx - c * 49;
            const float4 v = *(const float4*)(src + gbase + c * HW_ + q4 * 4);
            Xs[c][q4 * 4 + 0] = v.x;
            Xs[c][q4 * 4 + 1] = v.y;
            Xs[c][q4 * 4 + 2] = v.z;
            Xs[c][q4 * 4 + 3] = v.w;
        }
    }
    __syncthreads();
    const long pbase = (long)nt * HW_;
    const int c0 = (tid & 15) * 4;
    #pragma unroll
    for (int i = 0; i < 13; ++i) {
        const int idx = i * 256 + tid;
        if (idx < 3136) {
            const int hw = idx >> 4;
            ushort4v pk;
            #pragma unroll
            for (int e = 0; e < 4; ++e) pk[e] = f2bf(Xs[c0 + e][hw]);
            *(ushort4v*)(dst + (pbase + hw) * C_ + ct * 64 + c0) = pk;
        }
    }
}

// ---------------------------------------------------------------------------
// Padding masks. km stored as additive bias (0 / -1e38) in a PADDED [4][1600]
// layout (tail rows = -1e38). qm stays 1/0 at [n*S + s].
// ---------------------------------------------------------------------------
__global__ __launch_bounds__(256) void mask_kernel(
    const ushort_t* __restrict__ qbf, const ushort_t* __restrict__ kbf,
    float* __restrict__ qm, float* __restrict__ km)
{
    const int tid = threadIdx.x;
    const int w = tid >> 6, lane = tid & 63;
    const int p = blockIdx.x * 4 + w;
    const short8v qv = *(const short8v*)(qbf + (long)p * C_ + lane * 8);
    const short8v kv = *(const short8v*)(kbf + (long)p * C_ + lane * 8);
    float sq = 0.f, sk = 0.f;
    #pragma unroll
    for (int j = 0; j < 8; ++j) {
        sq += bf2f(((const ushort_t*)&qv)[j]);
        sk += bf2f(((const ushort_t*)&kv)[j]);
    }
    #pragma unroll
    for (int off = 32; off > 0; off >>= 1) {
        sq += __shfl_xor(sq, off, 64);
        sk += __shfl_xor(sk, off, 64);
    }
    if (lane == 0) {
        const int n = p / S_, s = p - n * S_;
        qm[p] = (sq != 0.f) ? 1.f : 0.f;
        km[n * KMP_ + s] = (sk != 0.f) ? 0.f : NEGL_;
    }
    if (blockIdx.x == 0 && tid < 128) {           // pad tail rows
        const int nn = tid >> 5;
        const int ss = S_ + (tid & 31);
        km[nn * KMP_ + ss] = NEGL_;
    }
}

// ---------------------------------------------------------------------------
// Projections: 1176 blocks (8 XCD chunks x 147), BM=128 p x BN=64 o (1 head).
// Double-buffered global_load_lds, ONE barrier per k-step (r13-verified).
// z=0 Q (pre-scaled by 0.125*log2e), z=1 K; z=2 V (out [b][d][s]).
// ---------------------------------------------------------------------------
__global__ __launch_bounds__(256) void proj_all(
    const ushort_t* __restrict__ qbf, const ushort_t* __restrict__ kbf,
    const ushort_t* __restrict__ vbf, const ushort_t* __restrict__ Wbf,
    const float* __restrict__ bq, const float* __restrict__ bk,
    const float* __restrict__ bv,
    ushort_t* __restrict__ Qh, ushort_t* __restrict__ Kh,
    ushort_t* __restrict__ Vt)
{
    __shared__ char lds[49152];   // 2 x (16KB X + 8KB W)

    const int fid = blockIdx.x;
    const int xcd = fid & 7;
    const int iin = fid >> 3;
    const int v = xcd * 147 + iin;           // 0..1175
    const int z = v / 392;                   // 392 = 49 ptiles x 8 heads
    const int rem = v - z * 392;
    const int ptile = rem >> 3;
    const int head = rem & 7;

    const ushort_t* Xbf = (z == 0) ? qbf : (z == 1) ? kbf : vbf;
    const ushort_t* Wz = Wbf + (long)z * 262144;
    const float* bias = (z == 0) ? bq : (z == 1) ? bk : bv;
    ushort_t* outp = (z == 0) ? Qh : (z == 1) ? Kh : Vt;
    const bool TR = (z == 2);
    const float osc = (z == 0) ? QSC_ : 1.0f;

    const int tid = threadIdx.x;
    const int w = tid >> 6, lane = tid & 63, lg = lane >> 4, lo = lane & 15;
    const int wr = w >> 1, wc = w & 1;
    const int p0 = ptile * 128;
    const int o0 = head * 64;

    const int wbase = (tid & 192) * 16;

    float4v acc[2][4];
    #pragma unroll
    for (int a = 0; a < 2; ++a)
        #pragma unroll
        for (int b = 0; b < 4; ++b) acc[a][b] = (float4v){0.f, 0.f, 0.f, 0.f};

    auto stage = [&](int buf, int k0) {
        char* Xl = lds + buf * 24576;
        char* Wl = Xl + 16384;
        #pragma unroll
        for (int i = 0; i < 4; ++i) {
            const int sl = tid + i * 256;
            const int row = sl >> 3, sir = sl & 7;
            const int c16 = sir ^ (row & 7);
            gload_lds16(Xbf + (long)(p0 + row) * C_ + k0 + c16 * 8,
                        Xl + i * 4096 + wbase);
        }
        #pragma unroll
        for (int i = 0; i < 2; ++i) {
            const int sl = tid + i * 256;
            const int row = sl >> 3, sir = sl & 7;
            const int c16 = sir ^ (row & 7);
            gload_lds16(Wz + (long)(o0 + row) * C_ + k0 + c16 * 8,
                        Wl + i * 4096 + wbase);
        }
    };

    stage(0, 0);
    #pragma unroll
    for (int kstep = 0; kstep < 8; ++kstep) {
        __syncthreads();
        if (kstep < 7) stage((kstep + 1) & 1, (kstep + 1) * 64);

        const char* Xl = lds + (kstep & 1) * 24576;
        const char* Wl = Xl + 16384;
        short8v wf[2][2], xf[4][2];
        #pragma unroll
        for (int a = 0; a < 2; ++a) {
            const int row = wc * 32 + a * 16 + lo;
            const int swr = (row & 7) << 4;
            #pragma unroll
            for (int ks = 0; ks < 2; ++ks) {
                const int base = row * 128 + ks * 64 + lg * 8;
                ((uint2*)&wf[a][ks])[0] = *(const uint2*)(Wl + (base ^ swr));
                ((uint2*)&wf[a][ks])[1] = *(const uint2*)(Wl + ((base + 32) ^ swr));
            }
        }
        #pragma unroll
        for (int b = 0; b < 4; ++b) {
            const int row = wr * 64 + b * 16 + lo;
            const int swr = (row & 7) << 4;
            #pragma unroll
            for (int ks = 0; ks < 2; ++ks) {
                const int base = row * 128 + ks * 64 + lg * 8;
                ((uint2*)&xf[b][ks])[0] = *(const uint2*)(Xl + (base ^ swr));
                ((uint2*)&xf[b][ks])[1] = *(const uint2*)(Xl + ((base + 32) ^ swr));
            }
        }
        __builtin_amdgcn_s_setprio(1);
        if (!TR) {
            #pragma unroll
            for (int ks = 0; ks < 2; ++ks)
                #pragma unroll
                for (int a = 0; a < 2; ++a)
                    #pragma unroll
                    for (int b = 0; b < 4; ++b)
                        acc[a][b] = mfma16(wf[a][ks], xf[b][ks], acc[a][b]);
        } else {
            #pragma unroll
            for (int ks = 0; ks < 2; ++ks)
                #pragma unroll
                for (int a = 0; a < 2; ++a)
                    #pragma unroll
                    for (int b = 0; b < 4; ++b)
                        acc[a][b] = mfma16(xf[b][ks], wf[a][ks], acc[a][b]);
        }
        __builtin_amdgcn_s_setprio(0);
    }

    if (!TR) {
        #pragma unroll
        for (int b = 0; b < 4; ++b) {
            const int p = p0 + wr * 64 + b * 16 + lo;
            const int nb = p / S_;
            const int s = p - nb * S_;
            #pragma unroll
            for (int a = 0; a < 2; ++a) {
                const int d0 = wc * 32 + a * 16 + lg * 4;
                const float4v bs = *(const float4v*)(bias + o0 + d0);
                ushort4v pk;
                #pragma unroll
                for (int e = 0; e < 4; ++e) {
                    float vv = acc[a][b][e] + bs[e];
                    vv = vv > 0.f ? vv : 0.f;
                    pk[e] = f2bf(vv * osc);
                }
                *(ushort4v*)(outp + ((long)(head * N_ + nb) * S_ + s) * D_ + d0) = pk;
            }
        }
    } else {
        #pragma unroll
        for (int a = 0; a < 2; ++a) {
            const int d = wc * 32 + a * 16 + lo;
            const float bsc = bias[o0 + d];
            #pragma unroll
            for (int b = 0; b < 4; ++b) {
                const int pb = p0 + wr * 64 + b * 16 + lg * 4;
                const int nb = pb / S_;
                const int s0 = pb - nb * S_;
                ushort4v pk;
                #pragma unroll
                for (int e = 0; e < 4; ++e) {
                    float vv = acc[a][b][e] + bsc;
                    vv = vv > 0.f ? vv : 0.f;
                    pk[e] = f2bf(vv);
                }
                *(ushort4v*)(outp + ((long)(head * N_ + nb) * D_ + d) * S_ + s0) = pk;
            }
        }
    }
}

// ---------------------------------------------------------------------------
// Split-K(x4) flash attention, QBLK=64 (r13 geometry). T4 counted-vmcnt:
// issue order {K, mask, V}; wait vmcnt(2) (K+mask done, V in flight) + raw
// barrier before QK^T; vmcnt(0) + raw barrier before PV so V's DMA latency
// overlaps QK^T+softmax. Full __syncthreads after PV protects the buffer.
// ---------------------------------------------------------------------------
__global__ __launch_bounds__(256) void attn_kernel(
    const ushort_t* __restrict__ Qh, const ushort_t* __restrict__ Kh,
    const ushort_t* __restrict__ Vt, const float* __restrict__ km,
    ushort_t* __restrict__ Pc, float* __restrict__ Ml)
{
    __shared__ char lds[16384 + 256];   // K 8KB | V 8KB | kms 256B

    const int tid = threadIdx.x;
    const int lane = tid & 63;
    const int w = tid >> 6;
    const int lg = lane >> 4;
    const int lo = lane & 15;

    const int split = blockIdx.y;               // 0..3
    const int t1 = 7 + split * 6;               // 7,13,19,25
    const int t0 = split ? (1 + split * 6) : 0; // 0,7,13,19

    const int fid = blockIdx.x;          // 0..799, XCD-aware decode
    const int x = fid & 7;
    const int j = fid >> 3;
    const int b = x + 8 * (j / 25);
    const int q0 = (j % 25) * 64;
    const int n = b & (N_ - 1);

    char* Kl = lds;
    char* Vl = lds + 8192;
    const float* kms = (const float*)(lds + 16384);
    const int wbase = (tid & 192) * 16;

    const int qrow = q0 + w * 16 + lo;
    const int qcl = qrow < S_ ? qrow : S_ - 1;
    const ushort_t* qp = Qh + ((long)b * S_ + qcl) * D_ + lg * 4;
    short8v qf[2];
    #pragma unroll
    for (int ks = 0; ks < 2; ++ks) {
        ((uint2*)&qf[ks])[0] = *(const uint2*)(qp + ks * 32);
        ((uint2*)&qf[ks])[1] = *(const uint2*)(qp + ks * 32 + 16);
    }

    float4v acc[4];
    #pragma unroll
    for (int dt = 0; dt < 4; ++dt) acc[dt] = (float4v){0.f, 0.f, 0.f, 0.f};
    float m_run = -INFINITY, l_run = 0.f;       // l_run per-lane partial

    auto stageK = [&](int kb) {
        #pragma unroll
        for (int i = 0; i < 2; ++i) {
            const int s = i * 256 + tid;
            const int row = s >> 3;
            const int c16 = (s & 7) ^ (row & 7);
            int krow = kb + row; if (krow >= S_) krow = S_ - 1;
            gload_lds16(Kh + ((long)b * S_ + krow) * D_ + c16 * 8,
                        Kl + i * 4096 + wbase);
        }
        if (w == 0)
            gload_lds4(km + (long)n * KMP_ + kb + lane, (void*)kms);
    };
    auto stageV = [&](int kb) {
        #pragma unroll
        for (int i = 0; i < 2; ++i) {
            const int s = i * 256 + tid;
            const int row = s >> 3;
            const int c16 = (s & 7) ^ (row & 7);
            int kc = kb + c16 * 8; if (kc > S_ - 8) kc = S_ - 8;
            gload_lds16(Vt + ((long)b * D_ + row) * S_ + kc,
                        Vl + i * 4096 + wbase);
        }
    };

    for (int t = t0; t < t1; ++t) {
        stageK(t * 64);
        stageV(t * 64);
        // K + mask done (2 V loads still in flight for every wave):
        asm volatile("s_waitcnt vmcnt(2)" ::: "memory");
        __builtin_amdgcn_s_barrier();

        float4v s[4];
        __builtin_amdgcn_s_setprio(1);
        #pragma unroll
        for (int kt = 0; kt < 4; ++kt) {
            s[kt] = (float4v){0.f, 0.f, 0.f, 0.f};
            #pragma unroll
            for (int ks = 0; ks < 2; ++ks) {
                const int row = kt * 16 + lo;
                const int base = row * 128 + ks * 64 + lg * 8;
                const int swr = (row & 7) << 4;
                short8v kf;
                ((uint2*)&kf)[0] = *(const uint2*)(Kl + (base ^ swr));
                ((uint2*)&kf)[1] = *(const uint2*)(Kl + ((base + 32) ^ swr));
                s[kt] = mfma16(kf, qf[ks], s[kt]);
            }
        }
        __builtin_amdgcn_s_setprio(0);

        // ---- exp2-domain softmax: bias add, max3 tree, deferred l reduce ----
        float p[4][4];
        #pragma unroll
        for (int kt = 0; kt < 4; ++kt) {
            const float4v bv4 = *(const float4v*)&kms[kt * 16 + lg * 4];
            #pragma unroll
            for (int r = 0; r < 4; ++r) p[kt][r] = s[kt][r] + bv4[r];
        }
        const float m1 = max3f(p[0][0], p[0][1], p[0][2]);
        const float m2 = max3f(p[0][3], p[1][0], p[1][1]);
        const float m3 = max3f(p[1][2], p[1][3], p[2][0]);
        const float m4 = max3f(p[2][1], p[2][2], p[2][3]);
        const float m5 = max3f(p[3][0], p[3][1], p[3][2]);
        float mx = max3f(max3f(m1, m2, m3), m4, fmaxf(m5, p[3][3]));
        mx = fmaxf(mx, __shfl_xor(mx, 16, 64));
        mx = fmaxf(mx, __shfl_xor(mx, 32, 64));
        float mn;
        if (__all(mx <= m_run + 8.f)) {
            mn = m_run;
        } else {
            mn = fmaxf(m_run, mx);
            const float alpha = exp2_fast(m_run - mn);
            m_run = mn;
            l_run *= alpha;
            #pragma unroll
            for (int dt = 0; dt < 4; ++dt)
                #pragma unroll
                for (int r = 0; r < 4; ++r) acc[dt][r] *= alpha;
        }
        float rs4[4];
        #pragma unroll
        for (int kt = 0; kt < 4; ++kt) {
            #pragma unroll
            for (int r = 0; r < 4; ++r) p[kt][r] = exp2_fast(p[kt][r] - mn);
            rs4[kt] = (p[kt][0] + p[kt][1]) + (p[kt][2] + p[kt][3]);
        }
        l_run += (rs4[0] + rs4[1]) + (rs4[2] + rs4[3]);

        short8v pf[2];
        #pragma unroll
        for (int kt = 0; kt < 4; ++kt) {
            const unsigned w0 = cvt_pk_bf16(p[kt][0], p[kt][1]);
            const unsigned w1 = cvt_pk_bf16(p[kt][2], p[kt][3]);
            ((unsigned*)&pf[kt >> 1])[(kt & 1) * 2] = w0;
            ((unsigned*)&pf[kt >> 1])[(kt & 1) * 2 + 1] = w1;
        }

        // V DMAs drained (latency overlapped with QK^T+softmax above):
        asm volatile("s_waitcnt vmcnt(0)" ::: "memory");
        __builtin_amdgcn_s_barrier();

        __builtin_amdgcn_s_setprio(1);
        #pragma unroll
        for (int dt = 0; dt < 4; ++dt) {
            #pragma unroll
            for (int ks = 0; ks < 2; ++ks) {
                const int row = dt * 16 + lo;
                const int base = row * 128 + ks * 64 + lg * 8;
                const int swr = (row & 7) << 4;
                short8v vf;
                ((uint2*)&vf)[0] = *(const uint2*)(Vl + (base ^ swr));
                ((uint2*)&vf)[1] = *(const uint2*)(Vl + ((base + 32) ^ swr));
                acc[dt] = mfma16(vf, pf[ks], acc[dt]);
            }
        }
        __builtin_amdgcn_s_setprio(0);
        __syncthreads();     // all reads done before next tile's DMAs
    }

    // final cross-lane l reduce (once per kernel)
    l_run += __shfl_xor(l_run, 16, 64);
    l_run += __shfl_xor(l_run, 32, 64);

    if (qrow < S_) {
        const long rbase = ((long)split * 32 + b) * S_ + qrow;
        if (lg == 0) {
            Ml[rbase * 2] = m_run;
            Ml[rbase * 2 + 1] = l_run;
        }
        ushort_t* P = Pc + rbase * 64;
        #pragma unroll
        for (int dt = 0; dt < 4; ++dt) {
            uint2 uu;
            uu.x = cvt_pk_bf16(acc[dt][0], acc[dt][1]);
            uu.y = cvt_pk_bf16(acc[dt][2], acc[dt][3]);
            *(uint2*)(P + dt * 16 + lg * 4) = uu;
        }
    }
}

// ---------------------------------------------------------------------------
// Fused split-K combine (exp2-domain lse merge, qm, 1/l) + LN stats.
// ---------------------------------------------------------------------------
__global__ __launch_bounds__(256) void combine_stats_kernel(
    const ushort_t* __restrict__ Pc, const float* __restrict__ Ml,
    const float* __restrict__ qm, const ushort_t* __restrict__ qbf,
    ushort_t* __restrict__ Om, float* __restrict__ stats)
{
    const int tid = threadIdx.x;
    const int wv = tid >> 6, lane = tid & 63;
    const long pos = (long)blockIdx.x * 4 + wv;     // n*S + q
    const int n = (int)(pos / S_);
    const int q = (int)(pos - (long)n * S_);
    const int head = lane >> 3;
    const int d0 = (lane & 7) * 8;

    long rb[4];
    float mv[4], lv[4];
    float M = -INFINITY;
    #pragma unroll
    for (int s = 0; s < 4; ++s) {
        rb[s] = ((long)(s * 32 + head * 4 + n) * S_ + q);
        const float2 ml = *(const float2*)(Ml + rb[s] * 2);
        mv[s] = ml.x; lv[s] = ml.y;
        M = fmaxf(M, ml.x);
    }
    float L = 0.f;
    float o[8] = {0.f, 0.f, 0.f, 0.f, 0.f, 0.f, 0.f, 0.f};
    #pragma unroll
    for (int s = 0; s < 4; ++s) {
        const float wgt = exp2_fast(mv[s] - M);
        L = fmaf(lv[s], wgt, L);
        const ushort4v a0 = *(const ushort4v*)(Pc + rb[s] * 64 + d0);
        const ushort4v a1 = *(const ushort4v*)(Pc + rb[s] * 64 + d0 + 4);
        #pragma unroll
        for (int e = 0; e < 4; ++e) {
            o[e] = fmaf(bf2f(a0[e]), wgt, o[e]);
            o[4 + e] = fmaf(bf2f(a1[e]), wgt, o[4 + e]);
        }
    }
    L = fmaxf(L, 1e-20f);
    const float scale = qm[pos] / L;
    const short8v qv = *(const short8v*)(qbf + pos * C_ + lane * 8);
    ushort4v ov0, ov1;
    float sum = 0.f, ssq = 0.f;
    #pragma unroll
    for (int e = 0; e < 8; ++e) {
        const ushort_t ob = f2bf(o[e] * scale);
        if (e < 4) ov0[e] = ob; else ov1[e - 4] = ob;
        const float v = bf2f(ob) + bf2f(((const ushort_t*)&qv)[e]);
        sum += v; ssq += v * v;
    }
    #pragma unroll
    for (int off = 32; off > 0; off >>= 1) {
        sum += __shfl_xor(sum, off, 64);
        ssq += __shfl_xor(ssq, off, 64);
    }
    *(ushort4v*)(Om + pos * C_ + lane * 8) = ov0;
    *(ushort4v*)(Om + pos * C_ + lane * 8 + 4) = ov1;
    if (lane == 0) {
        const float mean = sum * (1.f / 512.f);
        float var = (ssq - sum * mean) * (1.f / 511.f);
        var = var > 0.f ? var : 0.f;
        stats[pos * 2] = mean;
        stats[pos * 2 + 1] = 1.f / (sqrtf(var) + EPS_);
    }
}

// ---------------------------------------------------------------------------
// LN pass 2: normalize + gamma/beta, LDS-transposed, float4 writes
// ---------------------------------------------------------------------------
__global__ __launch_bounds__(256) void ln_write_kernel(
    const ushort_t* __restrict__ Om, const ushort_t* __restrict__ qbf,
    const float* __restrict__ stats, const float* __restrict__ gamma,
    const float* __restrict__ beta, float* __restrict__ out)
{
    __shared__ float Tl[64][197];
    const int nt = blockIdx.x;
    const int ct = blockIdx.y;
    const int tid = threadIdx.x;

    const int c0 = (tid & 15) * 4;
    float g[4], bb[4];
    #pragma unroll
    for (int e = 0; e < 4; ++e) {
        g[e] = gamma[ct * 64 + c0 + e];
        bb[e] = beta[ct * 64 + c0 + e];
    }

    #pragma unroll
    for (int i = 0; i < 13; ++i) {
        const int idx = i * 256 + tid;
        if (idx < 3136) {
            const int hw = idx >> 4;
            const long p = (long)nt * HW_ + hw;
            const float mean = stats[p * 2];
            const float inv = stats[p * 2 + 1];
            const ushort4v ov = *(const ushort4v*)(Om + p * C_ + ct * 64 + c0);
            const ushort4v qv = *(const ushort4v*)(qbf + p * C_ + ct * 64 + c0);
            #pragma unroll
            for (int e = 0; e < 4; ++e) {
                const float xv = bf2f(ov[e]) + bf2f(qv[e]);
                Tl[c0 + e][hw] = g[e] * (xv - mean) * inv + bb[e];
            }
        }
    }
    __syncthreads();
    const long obase = ((long)nt * C_ + ct * 64) * HW_;
    #pragma unroll
    for (int i = 0; i < 13; ++i) {
        const int idx = i * 256 + tid;
        if (idx < 3136) {
            const int c = idx / 49;
            const int q4 = idx - c * 49;
            float4 v;
            v.x = Tl[c][q4 * 4 + 0];
            v.y = Tl[c][q4 * 4 + 1];
            v.z = Tl[c][q4 * 4 + 2];
            v.w = Tl[c][q4 * 4 + 3];
            *(float4*)(out + obase + c * HW_ + q4 * 4) = v;
        }
    }
}

extern "C" void kernel_launch(void* const* d_in, const int* in_sizes, int n_in,
                              void* d_out, int out_size, void* d_ws, size_t ws_size,
                              hipStream_t stream) {
    const float* q_in  = (const float*)d_in[0];
    const float* k_in  = (const float*)d_in[1];
    const float* v_in  = (const float*)d_in[2];
    const float* Wq    = (const float*)d_in[3];
    const float* bq    = (const float*)d_in[4];
    const float* Wk    = (const float*)d_in[5];
    const float* bk    = (const float*)d_in[6];
    const float* Wv    = (const float*)d_in[7];
    const float* bv    = (const float*)d_in[8];
    const float* gamma = (const float*)d_in[9];
    const float* beta  = (const float*)d_in[10];
    float* out = (float*)d_out;

    const size_t PC = (size_t)P_TOT * C_;            // 3,211,264
    ushort_t* qbf = (ushort_t*)d_ws;
    ushort_t* kbf = qbf + PC;
    ushort_t* vbf = kbf + PC;
    ushort_t* Wbf = vbf + PC;                        // 3 x 512 x 512 bf16
    ushort_t* Qh  = Wbf + 3 * (size_t)C_ * C_;
    ushort_t* Kh  = Qh + PC;
    ushort_t* Vt  = Kh + PC;
    ushort_t* Om  = Vt + PC;                         // bf16
    ushort_t* Pc  = Om + PC;                         // 4*32*1568*64 bf16
    float* Ml    = (float*)(Pc + 4L * 32 * S_ * 64);
    float* stats = Ml + 4L * 32 * S_ * 2;
    float* qm    = stats + 2 * P_TOT;
    float* km    = qm + P_TOT;                       // padded [4][1600]

    transpose_kernel<<<dim3(32, 8, 4), 256, 0, stream>>>(
        q_in, k_in, v_in, qbf, kbf, vbf, Wq, Wk, Wv, Wbf);
    mask_kernel<<<P_TOT / 4, 256, 0, stream>>>(qbf, kbf, qm, km);
    proj_all<<<1176, 256, 0, stream>>>(qbf, kbf, vbf, Wbf, bq, bk, bv, Qh, Kh, Vt);
    attn_kernel<<<dim3(800, 4), 256, 0, stream>>>(Qh, Kh, Vt, km, Pc, Ml);
    combine_stats_kernel<<<P_TOT / 4, 256, 0, stream>>>(Pc, Ml, qm, qbf, Om, stats);
    ln_write_kernel<<<dim3(32, 8), 256, 0, stream>>>(Om, qbf, stats, gamma, beta, out);
}

// Round 16
// 100.328 us; speedup vs baseline: 1.0607x; 1.0125x over previous
//
#include <hip/hip_runtime.h>
#include <math.h>

#define N_ 4
#define T_ 8
#define C_ 512
#define H_ 14
#define W_ 14
#define HEADS_ 8
#define D_ 64
#define HW_ 196
#define S_ 1568
#define P_TOT 6272
#define KMP_ 1600        /* padded km row stride */
#define NEGL_ (-1.0e38f)
#define EPS_ 1e-8f
#define QSC_ 0.18033688011112042f   /* 0.125 * log2(e) */

typedef __attribute__((ext_vector_type(8))) short short8v;
typedef __attribute__((ext_vector_type(4))) float float4v;
typedef __attribute__((ext_vector_type(4))) unsigned short ushort4v;
typedef unsigned short ushort_t;

__device__ __forceinline__ ushort_t f2bf(float f) {
    union { float f; unsigned u; } a; a.f = f;
    unsigned r = (a.u + 0x7FFFu + ((a.u >> 16) & 1u)) >> 16;
    return (ushort_t)r;
}
__device__ __forceinline__ float bf2f(ushort_t u) {
    union { unsigned u; float f; } t; t.u = ((unsigned)u) << 16; return t.f;
}
__device__ __forceinline__ unsigned cvt_pk_bf16(float lo, float hi) {
    unsigned r;
    asm("v_cvt_pk_bf16_f32 %0, %1, %2" : "=v"(r) : "v"(lo), "v"(hi));
    return r;
}
__device__ __forceinline__ float exp2_fast(float x) {
    float r;
    asm("v_exp_f32 %0, %1" : "=v"(r) : "v"(x));
    return r;
}
__device__ __forceinline__ float max3f(float a, float b, float c) {
    float r;
    asm("v_max3_f32 %0, %1, %2, %3" : "=v"(r) : "v"(a), "v"(b), "v"(c));
    return r;
}
__device__ __forceinline__ float4v mfma16(short8v a, short8v b, float4v c) {
    return __builtin_amdgcn_mfma_f32_16x16x32_bf16(a, b, c, 0, 0, 0);
}
// Direct global -> LDS DMA. LDS dest = wave-uniform base + lane*size.
__device__ __forceinline__ void gload_lds16(const void* g, void* l) {
    __builtin_amdgcn_global_load_lds(
        (const __attribute__((address_space(1))) unsigned int*)g,
        (__attribute__((address_space(3))) unsigned int*)l,
        16, 0, 0);
}
__device__ __forceinline__ void gload_lds4(const void* g, void* l) {
    __builtin_amdgcn_global_load_lds(
        (const __attribute__((address_space(1))) unsigned int*)g,
        (__attribute__((address_space(3))) unsigned int*)l,
        4, 0, 0);
}

// ---------------------------------------------------------------------------
// Transpose pre-pass: (N,T,C,H,W) fp32 -> [p][c] bf16.  z==3: W fp32->bf16.
// ---------------------------------------------------------------------------
__global__ __launch_bounds__(256) void transpose_kernel(
    const float* __restrict__ q_in, const float* __restrict__ k_in,
    const float* __restrict__ v_in, ushort_t* __restrict__ qbf,
    ushort_t* __restrict__ kbf, ushort_t* __restrict__ vbf,
    const float* __restrict__ Wq, const float* __restrict__ Wk,
    const float* __restrict__ Wv, ushort_t* __restrict__ Wbf)
{
    __shared__ float Xs[64][197];
    const int z = blockIdx.z;
    const int nt = blockIdx.x;
    const int ct = blockIdx.y;
    const int tid = threadIdx.x;

    if (z == 3) {
        const int blk = nt * 8 + ct;
        #pragma unroll
        for (int i = 0; i < 3; ++i) {
            const int q = (blk * 3 + i) * 256 + tid;   // 0..196607
            const int zi = q >> 16;
            const int qi = q & 65535;
            const float* src = (zi == 0) ? Wq : (zi == 1) ? Wk : Wv;
            const float4 v = *(const float4*)(src + qi * 4);
            ushort4v pk;
            pk[0] = f2bf(v.x); pk[1] = f2bf(v.y);
            pk[2] = f2bf(v.z); pk[3] = f2bf(v.w);
            *(ushort4v*)(Wbf + (long)zi * 262144 + qi * 4) = pk;
        }
        return;
    }

    const float* src = (z == 0) ? q_in : (z == 1) ? k_in : v_in;
    ushort_t* dst = (z == 0) ? qbf : (z == 1) ? kbf : vbf;

    const long gbase = ((long)nt * C_ + ct * 64) * HW_;
    #pragma unroll
    for (int i = 0; i < 13; ++i) {
        const int idx = i * 256 + tid;          // 3136 float4 quads
        if (idx < 3136) {
            const int c = idx / 49;
            const int q4 = idx - c * 49;
            const float4 v = *(const float4*)(src + gbase + c * HW_ + q4 * 4);
            Xs[c][q4 * 4 + 0] = v.x;
            Xs[c][q4 * 4 + 1] = v.y;
            Xs[c][q4 * 4 + 2] = v.z;
            Xs[c][q4 * 4 + 3] = v.w;
        }
    }
    __syncthreads();
    const long pbase = (long)nt * HW_;
    const int c0 = (tid & 15) * 4;
    #pragma unroll
    for (int i = 0; i < 13; ++i) {
        const int idx = i * 256 + tid;
        if (idx < 3136) {
            const int hw = idx >> 4;
            ushort4v pk;
            #pragma unroll
            for (int e = 0; e < 4; ++e) pk[e] = f2bf(Xs[c0 + e][hw]);
            *(ushort4v*)(dst + (pbase + hw) * C_ + ct * 64 + c0) = pk;
        }
    }
}

// ---------------------------------------------------------------------------
// Padding masks. km stored as additive bias (0 / -1e38) in a PADDED [4][1600]
// layout (tail rows = -1e38). qm stays 1/0 at [n*S + s].
// ---------------------------------------------------------------------------
__global__ __launch_bounds__(256) void mask_kernel(
    const ushort_t* __restrict__ qbf, const ushort_t* __restrict__ kbf,
    float* __restrict__ qm, float* __restrict__ km)
{
    const int tid = threadIdx.x;
    const int w = tid >> 6, lane = tid & 63;
    const int p = blockIdx.x * 4 + w;
    const short8v qv = *(const short8v*)(qbf + (long)p * C_ + lane * 8);
    const short8v kv = *(const short8v*)(kbf + (long)p * C_ + lane * 8);
    float sq = 0.f, sk = 0.f;
    #pragma unroll
    for (int j = 0; j < 8; ++j) {
        sq += bf2f(((const ushort_t*)&qv)[j]);
        sk += bf2f(((const ushort_t*)&kv)[j]);
    }
    #pragma unroll
    for (int off = 32; off > 0; off >>= 1) {
        sq += __shfl_xor(sq, off, 64);
        sk += __shfl_xor(sk, off, 64);
    }
    if (lane == 0) {
        const int n = p / S_, s = p - n * S_;
        qm[p] = (sq != 0.f) ? 1.f : 0.f;
        km[n * KMP_ + s] = (sk != 0.f) ? 0.f : NEGL_;
    }
    if (blockIdx.x == 0 && tid < 128) {           // pad tail rows
        const int nn = tid >> 5;
        const int ss = S_ + (tid & 31);
        km[nn * KMP_ + ss] = NEGL_;
    }
}

// ---------------------------------------------------------------------------
// Projections: 1176 blocks (8 XCD chunks x 147), BM=128 p x BN=64 o (1 head).
// Double-buffered global_load_lds, ONE barrier per k-step (r13-verified).
// z=0 Q (pre-scaled by 0.125*log2e), z=1 K; z=2 V (out [b][d][s]).
// ---------------------------------------------------------------------------
__global__ __launch_bounds__(256) void proj_all(
    const ushort_t* __restrict__ qbf, const ushort_t* __restrict__ kbf,
    const ushort_t* __restrict__ vbf, const ushort_t* __restrict__ Wbf,
    const float* __restrict__ bq, const float* __restrict__ bk,
    const float* __restrict__ bv,
    ushort_t* __restrict__ Qh, ushort_t* __restrict__ Kh,
    ushort_t* __restrict__ Vt)
{
    __shared__ char lds[49152];   // 2 x (16KB X + 8KB W)

    const int fid = blockIdx.x;
    const int xcd = fid & 7;
    const int iin = fid >> 3;
    const int v = xcd * 147 + iin;           // 0..1175
    const int z = v / 392;                   // 392 = 49 ptiles x 8 heads
    const int rem = v - z * 392;
    const int ptile = rem >> 3;
    const int head = rem & 7;

    const ushort_t* Xbf = (z == 0) ? qbf : (z == 1) ? kbf : vbf;
    const ushort_t* Wz = Wbf + (long)z * 262144;
    const float* bias = (z == 0) ? bq : (z == 1) ? bk : bv;
    ushort_t* outp = (z == 0) ? Qh : (z == 1) ? Kh : Vt;
    const bool TR = (z == 2);
    const float osc = (z == 0) ? QSC_ : 1.0f;

    const int tid = threadIdx.x;
    const int w = tid >> 6, lane = tid & 63, lg = lane >> 4, lo = lane & 15;
    const int wr = w >> 1, wc = w & 1;
    const int p0 = ptile * 128;
    const int o0 = head * 64;

    const int wbase = (tid & 192) * 16;

    float4v acc[2][4];
    #pragma unroll
    for (int a = 0; a < 2; ++a)
        #pragma unroll
        for (int b = 0; b < 4; ++b) acc[a][b] = (float4v){0.f, 0.f, 0.f, 0.f};

    auto stage = [&](int buf, int k0) {
        char* Xl = lds + buf * 24576;
        char* Wl = Xl + 16384;
        #pragma unroll
        for (int i = 0; i < 4; ++i) {
            const int sl = tid + i * 256;
            const int row = sl >> 3, sir = sl & 7;
            const int c16 = sir ^ (row & 7);
            gload_lds16(Xbf + (long)(p0 + row) * C_ + k0 + c16 * 8,
                        Xl + i * 4096 + wbase);
        }
        #pragma unroll
        for (int i = 0; i < 2; ++i) {
            const int sl = tid + i * 256;
            const int row = sl >> 3, sir = sl & 7;
            const int c16 = sir ^ (row & 7);
            gload_lds16(Wz + (long)(o0 + row) * C_ + k0 + c16 * 8,
                        Wl + i * 4096 + wbase);
        }
    };

    stage(0, 0);
    #pragma unroll
    for (int kstep = 0; kstep < 8; ++kstep) {
        __syncthreads();
        if (kstep < 7) stage((kstep + 1) & 1, (kstep + 1) * 64);

        const char* Xl = lds + (kstep & 1) * 24576;
        const char* Wl = Xl + 16384;
        short8v wf[2][2], xf[4][2];
        #pragma unroll
        for (int a = 0; a < 2; ++a) {
            const int row = wc * 32 + a * 16 + lo;
            const int swr = (row & 7) << 4;
            #pragma unroll
            for (int ks = 0; ks < 2; ++ks) {
                const int base = row * 128 + ks * 64 + lg * 8;
                ((uint2*)&wf[a][ks])[0] = *(const uint2*)(Wl + (base ^ swr));
                ((uint2*)&wf[a][ks])[1] = *(const uint2*)(Wl + ((base + 32) ^ swr));
            }
        }
        #pragma unroll
        for (int b = 0; b < 4; ++b) {
            const int row = wr * 64 + b * 16 + lo;
            const int swr = (row & 7) << 4;
            #pragma unroll
            for (int ks = 0; ks < 2; ++ks) {
                const int base = row * 128 + ks * 64 + lg * 8;
                ((uint2*)&xf[b][ks])[0] = *(const uint2*)(Xl + (base ^ swr));
                ((uint2*)&xf[b][ks])[1] = *(const uint2*)(Xl + ((base + 32) ^ swr));
            }
        }
        __builtin_amdgcn_s_setprio(1);
        if (!TR) {
            #pragma unroll
            for (int ks = 0; ks < 2; ++ks)
                #pragma unroll
                for (int a = 0; a < 2; ++a)
                    #pragma unroll
                    for (int b = 0; b < 4; ++b)
                        acc[a][b] = mfma16(wf[a][ks], xf[b][ks], acc[a][b]);
        } else {
            #pragma unroll
            for (int ks = 0; ks < 2; ++ks)
                #pragma unroll
                for (int a = 0; a < 2; ++a)
                    #pragma unroll
                    for (int b = 0; b < 4; ++b)
                        acc[a][b] = mfma16(xf[b][ks], wf[a][ks], acc[a][b]);
        }
        __builtin_amdgcn_s_setprio(0);
    }

    if (!TR) {
        #pragma unroll
        for (int b = 0; b < 4; ++b) {
            const int p = p0 + wr * 64 + b * 16 + lo;
            const int nb = p / S_;
            const int s = p - nb * S_;
            #pragma unroll
            for (int a = 0; a < 2; ++a) {
                const int d0 = wc * 32 + a * 16 + lg * 4;
                const float4v bs = *(const float4v*)(bias + o0 + d0);
                ushort4v pk;
                #pragma unroll
                for (int e = 0; e < 4; ++e) {
                    float vv = acc[a][b][e] + bs[e];
                    vv = vv > 0.f ? vv : 0.f;
                    pk[e] = f2bf(vv * osc);
                }
                *(ushort4v*)(outp + ((long)(head * N_ + nb) * S_ + s) * D_ + d0) = pk;
            }
        }
    } else {
        #pragma unroll
        for (int a = 0; a < 2; ++a) {
            const int d = wc * 32 + a * 16 + lo;
            const float bsc = bias[o0 + d];
            #pragma unroll
            for (int b = 0; b < 4; ++b) {
                const int pb = p0 + wr * 64 + b * 16 + lg * 4;
                const int nb = pb / S_;
                const int s0 = pb - nb * S_;
                ushort4v pk;
                #pragma unroll
                for (int e = 0; e < 4; ++e) {
                    float vv = acc[a][b][e] + bsc;
                    vv = vv > 0.f ? vv : 0.f;
                    pk[e] = f2bf(vv);
                }
                *(ushort4v*)(outp + ((long)(head * N_ + nb) * D_ + d) * S_ + s0) = pk;
            }
        }
    }
}

// ---------------------------------------------------------------------------
// Split-K(x4) flash attention, QBLK=64 (r15-verified, 52.4us plateau).
// ---------------------------------------------------------------------------
__global__ __launch_bounds__(256) void attn_kernel(
    const ushort_t* __restrict__ Qh, const ushort_t* __restrict__ Kh,
    const ushort_t* __restrict__ Vt, const float* __restrict__ km,
    ushort_t* __restrict__ Pc, float* __restrict__ Ml)
{
    __shared__ char lds[16384 + 256];   // K 8KB | V 8KB | kms 256B

    const int tid = threadIdx.x;
    const int lane = tid & 63;
    const int w = tid >> 6;
    const int lg = lane >> 4;
    const int lo = lane & 15;

    const int split = blockIdx.y;               // 0..3
    const int t1 = 7 + split * 6;               // 7,13,19,25
    const int t0 = split ? (1 + split * 6) : 0; // 0,7,13,19

    const int fid = blockIdx.x;          // 0..799, XCD-aware decode
    const int x = fid & 7;
    const int j = fid >> 3;
    const int b = x + 8 * (j / 25);
    const int q0 = (j % 25) * 64;
    const int n = b & (N_ - 1);

    char* Kl = lds;
    char* Vl = lds + 8192;
    const float* kms = (const float*)(lds + 16384);
    const int wbase = (tid & 192) * 16;

    const int qrow = q0 + w * 16 + lo;
    const int qcl = qrow < S_ ? qrow : S_ - 1;
    const ushort_t* qp = Qh + ((long)b * S_ + qcl) * D_ + lg * 4;
    short8v qf[2];
    #pragma unroll
    for (int ks = 0; ks < 2; ++ks) {
        ((uint2*)&qf[ks])[0] = *(const uint2*)(qp + ks * 32);
        ((uint2*)&qf[ks])[1] = *(const uint2*)(qp + ks * 32 + 16);
    }

    float4v acc[4];
    #pragma unroll
    for (int dt = 0; dt < 4; ++dt) acc[dt] = (float4v){0.f, 0.f, 0.f, 0.f};
    float m_run = -INFINITY, l_run = 0.f;       // l_run per-lane partial

    auto stageK = [&](int kb) {
        #pragma unroll
        for (int i = 0; i < 2; ++i) {
            const int s = i * 256 + tid;
            const int row = s >> 3;
            const int c16 = (s & 7) ^ (row & 7);
            int krow = kb + row; if (krow >= S_) krow = S_ - 1;
            gload_lds16(Kh + ((long)b * S_ + krow) * D_ + c16 * 8,
                        Kl + i * 4096 + wbase);
        }
        if (w == 0)
            gload_lds4(km + (long)n * KMP_ + kb + lane, (void*)kms);
    };
    auto stageV = [&](int kb) {
        #pragma unroll
        for (int i = 0; i < 2; ++i) {
            const int s = i * 256 + tid;
            const int row = s >> 3;
            const int c16 = (s & 7) ^ (row & 7);
            int kc = kb + c16 * 8; if (kc > S_ - 8) kc = S_ - 8;
            gload_lds16(Vt + ((long)b * D_ + row) * S_ + kc,
                        Vl + i * 4096 + wbase);
        }
    };

    for (int t = t0; t < t1; ++t) {
        stageK(t * 64);
        stageV(t * 64);
        asm volatile("s_waitcnt vmcnt(2)" ::: "memory");
        __builtin_amdgcn_s_barrier();

        float4v s[4];
        __builtin_amdgcn_s_setprio(1);
        #pragma unroll
        for (int kt = 0; kt < 4; ++kt) {
            s[kt] = (float4v){0.f, 0.f, 0.f, 0.f};
            #pragma unroll
            for (int ks = 0; ks < 2; ++ks) {
                const int row = kt * 16 + lo;
                const int base = row * 128 + ks * 64 + lg * 8;
                const int swr = (row & 7) << 4;
                short8v kf;
                ((uint2*)&kf)[0] = *(const uint2*)(Kl + (base ^ swr));
                ((uint2*)&kf)[1] = *(const uint2*)(Kl + ((base + 32) ^ swr));
                s[kt] = mfma16(kf, qf[ks], s[kt]);
            }
        }
        __builtin_amdgcn_s_setprio(0);

        // ---- exp2-domain softmax: bias add, max3 tree, deferred l reduce ----
        float p[4][4];
        #pragma unroll
        for (int kt = 0; kt < 4; ++kt) {
            const float4v bv4 = *(const float4v*)&kms[kt * 16 + lg * 4];
            #pragma unroll
            for (int r = 0; r < 4; ++r) p[kt][r] = s[kt][r] + bv4[r];
        }
        const float m1 = max3f(p[0][0], p[0][1], p[0][2]);
        const float m2 = max3f(p[0][3], p[1][0], p[1][1]);
        const float m3 = max3f(p[1][2], p[1][3], p[2][0]);
        const float m4 = max3f(p[2][1], p[2][2], p[2][3]);
        const float m5 = max3f(p[3][0], p[3][1], p[3][2]);
        float mx = max3f(max3f(m1, m2, m3), m4, fmaxf(m5, p[3][3]));
        mx = fmaxf(mx, __shfl_xor(mx, 16, 64));
        mx = fmaxf(mx, __shfl_xor(mx, 32, 64));
        float mn;
        if (__all(mx <= m_run + 8.f)) {
            mn = m_run;
        } else {
            mn = fmaxf(m_run, mx);
            const float alpha = exp2_fast(m_run - mn);
            m_run = mn;
            l_run *= alpha;
            #pragma unroll
            for (int dt = 0; dt < 4; ++dt)
                #pragma unroll
                for (int r = 0; r < 4; ++r) acc[dt][r] *= alpha;
        }
        float rs4[4];
        #pragma unroll
        for (int kt = 0; kt < 4; ++kt) {
            #pragma unroll
            for (int r = 0; r < 4; ++r) p[kt][r] = exp2_fast(p[kt][r] - mn);
            rs4[kt] = (p[kt][0] + p[kt][1]) + (p[kt][2] + p[kt][3]);
        }
        l_run += (rs4[0] + rs4[1]) + (rs4[2] + rs4[3]);

        short8v pf[2];
        #pragma unroll
        for (int kt = 0; kt < 4; ++kt) {
            const unsigned w0 = cvt_pk_bf16(p[kt][0], p[kt][1]);
            const unsigned w1 = cvt_pk_bf16(p[kt][2], p[kt][3]);
            ((unsigned*)&pf[kt >> 1])[(kt & 1) * 2] = w0;
            ((unsigned*)&pf[kt >> 1])[(kt & 1) * 2 + 1] = w1;
        }

        asm volatile("s_waitcnt vmcnt(0)" ::: "memory");
        __builtin_amdgcn_s_barrier();

        __builtin_amdgcn_s_setprio(1);
        #pragma unroll
        for (int dt = 0; dt < 4; ++dt) {
            #pragma unroll
            for (int ks = 0; ks < 2; ++ks) {
                const int row = dt * 16 + lo;
                const int base = row * 128 + ks * 64 + lg * 8;
                const int swr = (row & 7) << 4;
                short8v vf;
                ((uint2*)&vf)[0] = *(const uint2*)(Vl + (base ^ swr));
                ((uint2*)&vf)[1] = *(const uint2*)(Vl + ((base + 32) ^ swr));
                acc[dt] = mfma16(vf, pf[ks], acc[dt]);
            }
        }
        __builtin_amdgcn_s_setprio(0);
        __syncthreads();
    }

    // final cross-lane l reduce (once per kernel)
    l_run += __shfl_xor(l_run, 16, 64);
    l_run += __shfl_xor(l_run, 32, 64);

    if (qrow < S_) {
        const long rbase = ((long)split * 32 + b) * S_ + qrow;
        if (lg == 0) {
            Ml[rbase * 2] = m_run;
            Ml[rbase * 2 + 1] = l_run;
        }
        ushort_t* P = Pc + rbase * 64;
        #pragma unroll
        for (int dt = 0; dt < 4; ++dt) {
            uint2 uu;
            uu.x = cvt_pk_bf16(acc[dt][0], acc[dt][1]);
            uu.y = cvt_pk_bf16(acc[dt][2], acc[dt][3]);
            *(uint2*)(P + dt * 16 + lg * 4) = uu;
        }
    }
}

// ---------------------------------------------------------------------------
// Fused split-K combine + residual + FULL LayerNorm (normalize inline).
// Butterfly reduce leaves sum/ssq in ALL lanes, so each lane can finish
// y = gamma*(v-mean)*inv + beta for its 8 channels. Om holds final bf16 y.
// ---------------------------------------------------------------------------
__global__ __launch_bounds__(256) void combine_ln_kernel(
    const ushort_t* __restrict__ Pc, const float* __restrict__ Ml,
    const float* __restrict__ qm, const ushort_t* __restrict__ qbf,
    const float* __restrict__ gamma, const float* __restrict__ beta,
    ushort_t* __restrict__ Om)
{
    const int tid = threadIdx.x;
    const int wv = tid >> 6, lane = tid & 63;
    const long pos = (long)blockIdx.x * 4 + wv;     // n*S + q
    const int n = (int)(pos / S_);
    const int q = (int)(pos - (long)n * S_);
    const int head = lane >> 3;
    const int d0 = (lane & 7) * 8;

    long rb[4];
    float mv[4], lv[4];
    float M = -INFINITY;
    #pragma unroll
    for (int s = 0; s < 4; ++s) {
        rb[s] = ((long)(s * 32 + head * 4 + n) * S_ + q);
        const float2 ml = *(const float2*)(Ml + rb[s] * 2);
        mv[s] = ml.x; lv[s] = ml.y;
        M = fmaxf(M, ml.x);
    }
    float L = 0.f;
    float o[8] = {0.f, 0.f, 0.f, 0.f, 0.f, 0.f, 0.f, 0.f};
    #pragma unroll
    for (int s = 0; s < 4; ++s) {
        const float wgt = exp2_fast(mv[s] - M);
        L = fmaf(lv[s], wgt, L);
        const ushort4v a0 = *(const ushort4v*)(Pc + rb[s] * 64 + d0);
        const ushort4v a1 = *(const ushort4v*)(Pc + rb[s] * 64 + d0 + 4);
        #pragma unroll
        for (int e = 0; e < 4; ++e) {
            o[e] = fmaf(bf2f(a0[e]), wgt, o[e]);
            o[4 + e] = fmaf(bf2f(a1[e]), wgt, o[4 + e]);
        }
    }
    L = fmaxf(L, 1e-20f);
    const float scale = qm[pos] / L;
    const short8v qv = *(const short8v*)(qbf + pos * C_ + lane * 8);
    float v8[8];
    float sum = 0.f, ssq = 0.f;
    #pragma unroll
    for (int e = 0; e < 8; ++e) {
        const float v = o[e] * scale + bf2f(((const ushort_t*)&qv)[e]);
        v8[e] = v;
        sum += v; ssq += v * v;
    }
    #pragma unroll
    for (int off = 32; off > 0; off >>= 1) {
        sum += __shfl_xor(sum, off, 64);
        ssq += __shfl_xor(ssq, off, 64);
    }
    const float mean = sum * (1.f / 512.f);
    float var = (ssq - sum * mean) * (1.f / 511.f);
    var = var > 0.f ? var : 0.f;
    const float inv = 1.f / (sqrtf(var) + EPS_);

    const float4v g0 = *(const float4v*)(gamma + lane * 8);
    const float4v g1 = *(const float4v*)(gamma + lane * 8 + 4);
    const float4v b0 = *(const float4v*)(beta + lane * 8);
    const float4v b1 = *(const float4v*)(beta + lane * 8 + 4);
    ushort4v ov0, ov1;
    #pragma unroll
    for (int e = 0; e < 4; ++e) {
        ov0[e] = f2bf(g0[e] * (v8[e] - mean) * inv + b0[e]);
        ov1[e] = f2bf(g1[e] * (v8[4 + e] - mean) * inv + b1[e]);
    }
    *(ushort4v*)(Om + pos * C_ + lane * 8) = ov0;
    *(ushort4v*)(Om + pos * C_ + lane * 8 + 4) = ov1;
}

// ---------------------------------------------------------------------------
// Output transpose: Om (bf16, [p][c], already LayerNormed) -> fp32 NTCHW.
// ---------------------------------------------------------------------------
__global__ __launch_bounds__(256) void ln_write_kernel(
    const ushort_t* __restrict__ Om, float* __restrict__ out)
{
    __shared__ float Tl[64][197];
    const int nt = blockIdx.x;
    const int ct = blockIdx.y;
    const int tid = threadIdx.x;

    const int c0 = (tid & 15) * 4;
    #pragma unroll
    for (int i = 0; i < 13; ++i) {
        const int idx = i * 256 + tid;
        if (idx < 3136) {
            const int hw = idx >> 4;
            const long p = (long)nt * HW_ + hw;
            const ushort4v ov = *(const ushort4v*)(Om + p * C_ + ct * 64 + c0);
            #pragma unroll
            for (int e = 0; e < 4; ++e) Tl[c0 + e][hw] = bf2f(ov[e]);
        }
    }
    __syncthreads();
    const long obase = ((long)nt * C_ + ct * 64) * HW_;
    #pragma unroll
    for (int i = 0; i < 13; ++i) {
        const int idx = i * 256 + tid;
        if (idx < 3136) {
            const int c = idx / 49;
            const int q4 = idx - c * 49;
            float4 v;
            v.x = Tl[c][q4 * 4 + 0];
            v.y = Tl[c][q4 * 4 + 1];
            v.z = Tl[c][q4 * 4 + 2];
            v.w = Tl[c][q4 * 4 + 3];
            *(float4*)(out + obase + c * HW_ + q4 * 4) = v;
        }
    }
}

extern "C" void kernel_launch(void* const* d_in, const int* in_sizes, int n_in,
                              void* d_out, int out_size, void* d_ws, size_t ws_size,
                              hipStream_t stream) {
    const float* q_in  = (const float*)d_in[0];
    const float* k_in  = (const float*)d_in[1];
    const float* v_in  = (const float*)d_in[2];
    const float* Wq    = (const float*)d_in[3];
    const float* bq    = (const float*)d_in[4];
    const float* Wk    = (const float*)d_in[5];
    const float* bk    = (const float*)d_in[6];
    const float* Wv    = (const float*)d_in[7];
    const float* bv    = (const float*)d_in[8];
    const float* gamma = (const float*)d_in[9];
    const float* beta  = (const float*)d_in[10];
    float* out = (float*)d_out;

    const size_t PC = (size_t)P_TOT * C_;            // 3,211,264
    ushort_t* qbf = (ushort_t*)d_ws;
    ushort_t* kbf = qbf + PC;
    ushort_t* vbf = kbf + PC;
    ushort_t* Wbf = vbf + PC;                        // 3 x 512 x 512 bf16
    ushort_t* Qh  = Wbf + 3 * (size_t)C_ * C_;
    ushort_t* Kh  = Qh + PC;
    ushort_t* Vt  = Kh + PC;
    ushort_t* Om  = Vt + PC;                         // bf16 (final LN'd values)
    ushort_t* Pc  = Om + PC;                         // 4*32*1568*64 bf16
    float* Ml    = (float*)(Pc + 4L * 32 * S_ * 64);
    float* qm    = Ml + 4L * 32 * S_ * 2;
    float* km    = qm + P_TOT;                       // padded [4][1600]

    transpose_kernel<<<dim3(32, 8, 4), 256, 0, stream>>>(
        q_in, k_in, v_in, qbf, kbf, vbf, Wq, Wk, Wv, Wbf);
    mask_kernel<<<P_TOT / 4, 256, 0, stream>>>(qbf, kbf, qm, km);
    proj_all<<<1176, 256, 0, stream>>>(qbf, kbf, vbf, Wbf, bq, bk, bv, Qh, Kh, Vt);
    attn_kernel<<<dim3(800, 4), 256, 0, stream>>>(Qh, Kh, Vt, km, Pc, Ml);
    combine_ln_kernel<<<P_TOT / 4, 256, 0, stream>>>(Pc, Ml, qm, qbf, gamma, beta, Om);
    ln_write_kernel<<<dim3(32, 8), 256, 0, stream>>>(Om, out);
}

// Round 17
// 94.250 us; speedup vs baseline: 1.1291x; 1.0645x over previous
//
#include <hip/hip_runtime.h>
#include <math.h>

#define N_ 4
#define T_ 8
#define C_ 512
#define H_ 14
#define W_ 14
#define HEADS_ 8
#define D_ 64
#define HW_ 196
#define S_ 1568
#define P_TOT 6272
#define KMP_ 1600        /* padded km row stride */
#define NEGL_ (-1.0e38f)
#define EPS_ 1e-8f
#define QSC_ 0.18033688011112042f   /* 0.125 * log2(e) */

typedef __attribute__((ext_vector_type(8))) short short8v;
typedef __attribute__((ext_vector_type(4))) float float4v;
typedef __attribute__((ext_vector_type(4))) unsigned short ushort4v;
typedef unsigned short ushort_t;

__device__ __forceinline__ ushort_t f2bf(float f) {
    union { float f; unsigned u; } a; a.f = f;
    unsigned r = (a.u + 0x7FFFu + ((a.u >> 16) & 1u)) >> 16;
    return (ushort_t)r;
}
__device__ __forceinline__ float bf2f(ushort_t u) {
    union { unsigned u; float f; } t; t.u = ((unsigned)u) << 16; return t.f;
}
__device__ __forceinline__ unsigned cvt_pk_bf16(float lo, float hi) {
    unsigned r;
    asm("v_cvt_pk_bf16_f32 %0, %1, %2" : "=v"(r) : "v"(lo), "v"(hi));
    return r;
}
__device__ __forceinline__ float exp2_fast(float x) {
    float r;
    asm("v_exp_f32 %0, %1" : "=v"(r) : "v"(x));
    return r;
}
__device__ __forceinline__ float4v mfma16(short8v a, short8v b, float4v c) {
    return __builtin_amdgcn_mfma_f32_16x16x32_bf16(a, b, c, 0, 0, 0);
}
// Direct global -> LDS DMA. LDS dest = wave-uniform base + lane*size.
__device__ __forceinline__ void gload_lds16(const void* g, void* l) {
    __builtin_amdgcn_global_load_lds(
        (const __attribute__((address_space(1))) unsigned int*)g,
        (__attribute__((address_space(3))) unsigned int*)l,
        16, 0, 0);
}
__device__ __forceinline__ void gload_lds4(const void* g, void* l) {
    __builtin_amdgcn_global_load_lds(
        (const __attribute__((address_space(1))) unsigned int*)g,
        (__attribute__((address_space(3))) unsigned int*)l,
        4, 0, 0);
}

// ---------------------------------------------------------------------------
// Transpose pre-pass: (N,T,C,H,W) fp32 -> [p][c] bf16.  z==3: W fp32->bf16.
// ---------------------------------------------------------------------------
__global__ __launch_bounds__(256) void transpose_kernel(
    const float* __restrict__ q_in, const float* __restrict__ k_in,
    const float* __restrict__ v_in, ushort_t* __restrict__ qbf,
    ushort_t* __restrict__ kbf, ushort_t* __restrict__ vbf,
    const float* __restrict__ Wq, const float* __restrict__ Wk,
    const float* __restrict__ Wv, ushort_t* __restrict__ Wbf)
{
    __shared__ float Xs[64][197];
    const int z = blockIdx.z;
    const int nt = blockIdx.x;
    const int ct = blockIdx.y;
    const int tid = threadIdx.x;

    if (z == 3) {
        const int blk = nt * 8 + ct;
        #pragma unroll
        for (int i = 0; i < 3; ++i) {
            const int q = (blk * 3 + i) * 256 + tid;   // 0..196607
            const int zi = q >> 16;
            const int qi = q & 65535;
            const float* src = (zi == 0) ? Wq : (zi == 1) ? Wk : Wv;
            const float4 v = *(const float4*)(src + qi * 4);
            ushort4v pk;
            pk[0] = f2bf(v.x); pk[1] = f2bf(v.y);
            pk[2] = f2bf(v.z); pk[3] = f2bf(v.w);
            *(ushort4v*)(Wbf + (long)zi * 262144 + qi * 4) = pk;
        }
        return;
    }

    const float* src = (z == 0) ? q_in : (z == 1) ? k_in : v_in;
    ushort_t* dst = (z == 0) ? qbf : (z == 1) ? kbf : vbf;

    const long gbase = ((long)nt * C_ + ct * 64) * HW_;
    #pragma unroll
    for (int i = 0; i < 13; ++i) {
        const int idx = i * 256 + tid;          // 3136 float4 quads
        if (idx < 3136) {
            const int c = idx / 49;
            const int q4 = idx - c * 49;
            const float4 v = *(const float4*)(src + gbase + c * HW_ + q4 * 4);
            Xs[c][q4 * 4 + 0] = v.x;
            Xs[c][q4 * 4 + 1] = v.y;
            Xs[c][q4 * 4 + 2] = v.z;
            Xs[c][q4 * 4 + 3] = v.w;
        }
    }
    __syncthreads();
    const long pbase = (long)nt * HW_;
    const int c0 = (tid & 15) * 4;
    #pragma unroll
    for (int i = 0; i < 13; ++i) {
        const int idx = i * 256 + tid;
        if (idx < 3136) {
            const int hw = idx >> 4;
            ushort4v pk;
            #pragma unroll
            for (int e = 0; e < 4; ++e) pk[e] = f2bf(Xs[c0 + e][hw]);
            *(ushort4v*)(dst + (pbase + hw) * C_ + ct * 64 + c0) = pk;
        }
    }
}

// ---------------------------------------------------------------------------
// Padding masks. km stored as additive bias (0 / -1e38) in a PADDED [4][1600]
// layout (tail rows = -1e38). qm stays 1/0 at [n*S + s].
// ---------------------------------------------------------------------------
__global__ __launch_bounds__(256) void mask_kernel(
    const ushort_t* __restrict__ qbf, const ushort_t* __restrict__ kbf,
    float* __restrict__ qm, float* __restrict__ km)
{
    const int tid = threadIdx.x;
    const int w = tid >> 6, lane = tid & 63;
    const int p = blockIdx.x * 4 + w;
    const short8v qv = *(const short8v*)(qbf + (long)p * C_ + lane * 8);
    const short8v kv = *(const short8v*)(kbf + (long)p * C_ + lane * 8);
    float sq = 0.f, sk = 0.f;
    #pragma unroll
    for (int j = 0; j < 8; ++j) {
        sq += bf2f(((const ushort_t*)&qv)[j]);
        sk += bf2f(((const ushort_t*)&kv)[j]);
    }
    #pragma unroll
    for (int off = 32; off > 0; off >>= 1) {
        sq += __shfl_xor(sq, off, 64);
        sk += __shfl_xor(sk, off, 64);
    }
    if (lane == 0) {
        const int n = p / S_, s = p - n * S_;
        qm[p] = (sq != 0.f) ? 1.f : 0.f;
        km[n * KMP_ + s] = (sk != 0.f) ? 0.f : NEGL_;
    }
    if (blockIdx.x == 0 && tid < 128) {           // pad tail rows
        const int nn = tid >> 5;
        const int ss = S_ + (tid & 31);
        km[nn * KMP_ + ss] = NEGL_;
    }
}

// ---------------------------------------------------------------------------
// Projections: 1176 blocks (8 XCD chunks x 147), BM=128 p x BN=64 o (1 head).
// Double-buffered global_load_lds, ONE barrier per k-step (r13-verified).
// z=0 Q (pre-scaled by 0.125*log2e), z=1 K; z=2 V (out [b][d][s]).
// ---------------------------------------------------------------------------
__global__ __launch_bounds__(256) void proj_all(
    const ushort_t* __restrict__ qbf, const ushort_t* __restrict__ kbf,
    const ushort_t* __restrict__ vbf, const ushort_t* __restrict__ Wbf,
    const float* __restrict__ bq, const float* __restrict__ bk,
    const float* __restrict__ bv,
    ushort_t* __restrict__ Qh, ushort_t* __restrict__ Kh,
    ushort_t* __restrict__ Vt)
{
    __shared__ char lds[49152];   // 2 x (16KB X + 8KB W)

    const int fid = blockIdx.x;
    const int xcd = fid & 7;
    const int iin = fid >> 3;
    const int v = xcd * 147 + iin;           // 0..1175
    const int z = v / 392;                   // 392 = 49 ptiles x 8 heads
    const int rem = v - z * 392;
    const int ptile = rem >> 3;
    const int head = rem & 7;

    const ushort_t* Xbf = (z == 0) ? qbf : (z == 1) ? kbf : vbf;
    const ushort_t* Wz = Wbf + (long)z * 262144;
    const float* bias = (z == 0) ? bq : (z == 1) ? bk : bv;
    ushort_t* outp = (z == 0) ? Qh : (z == 1) ? Kh : Vt;
    const bool TR = (z == 2);
    const float osc = (z == 0) ? QSC_ : 1.0f;

    const int tid = threadIdx.x;
    const int w = tid >> 6, lane = tid & 63, lg = lane >> 4, lo = lane & 15;
    const int wr = w >> 1, wc = w & 1;
    const int p0 = ptile * 128;
    const int o0 = head * 64;

    const int wbase = (tid & 192) * 16;

    float4v acc[2][4];
    #pragma unroll
    for (int a = 0; a < 2; ++a)
        #pragma unroll
        for (int b = 0; b < 4; ++b) acc[a][b] = (float4v){0.f, 0.f, 0.f, 0.f};

    auto stage = [&](int buf, int k0) {
        char* Xl = lds + buf * 24576;
        char* Wl = Xl + 16384;
        #pragma unroll
        for (int i = 0; i < 4; ++i) {
            const int sl = tid + i * 256;
            const int row = sl >> 3, sir = sl & 7;
            const int c16 = sir ^ (row & 7);
            gload_lds16(Xbf + (long)(p0 + row) * C_ + k0 + c16 * 8,
                        Xl + i * 4096 + wbase);
        }
        #pragma unroll
        for (int i = 0; i < 2; ++i) {
            const int sl = tid + i * 256;
            const int row = sl >> 3, sir = sl & 7;
            const int c16 = sir ^ (row & 7);
            gload_lds16(Wz + (long)(o0 + row) * C_ + k0 + c16 * 8,
                        Wl + i * 4096 + wbase);
        }
    };

    stage(0, 0);
    #pragma unroll
    for (int kstep = 0; kstep < 8; ++kstep) {
        __syncthreads();
        if (kstep < 7) stage((kstep + 1) & 1, (kstep + 1) * 64);

        const char* Xl = lds + (kstep & 1) * 24576;
        const char* Wl = Xl + 16384;
        short8v wf[2][2], xf[4][2];
        #pragma unroll
        for (int a = 0; a < 2; ++a) {
            const int row = wc * 32 + a * 16 + lo;
            const int swr = (row & 7) << 4;
            #pragma unroll
            for (int ks = 0; ks < 2; ++ks) {
                const int base = row * 128 + ks * 64 + lg * 8;
                ((uint2*)&wf[a][ks])[0] = *(const uint2*)(Wl + (base ^ swr));
                ((uint2*)&wf[a][ks])[1] = *(const uint2*)(Wl + ((base + 32) ^ swr));
            }
        }
        #pragma unroll
        for (int b = 0; b < 4; ++b) {
            const int row = wr * 64 + b * 16 + lo;
            const int swr = (row & 7) << 4;
            #pragma unroll
            for (int ks = 0; ks < 2; ++ks) {
                const int base = row * 128 + ks * 64 + lg * 8;
                ((uint2*)&xf[b][ks])[0] = *(const uint2*)(Xl + (base ^ swr));
                ((uint2*)&xf[b][ks])[1] = *(const uint2*)(Xl + ((base + 32) ^ swr));
            }
        }
        __builtin_amdgcn_s_setprio(1);
        if (!TR) {
            #pragma unroll
            for (int ks = 0; ks < 2; ++ks)
                #pragma unroll
                for (int a = 0; a < 2; ++a)
                    #pragma unroll
                    for (int b = 0; b < 4; ++b)
                        acc[a][b] = mfma16(wf[a][ks], xf[b][ks], acc[a][b]);
        } else {
            #pragma unroll
            for (int ks = 0; ks < 2; ++ks)
                #pragma unroll
                for (int a = 0; a < 2; ++a)
                    #pragma unroll
                    for (int b = 0; b < 4; ++b)
                        acc[a][b] = mfma16(xf[b][ks], wf[a][ks], acc[a][b]);
        }
        __builtin_amdgcn_s_setprio(0);
    }

    if (!TR) {
        #pragma unroll
        for (int b = 0; b < 4; ++b) {
            const int p = p0 + wr * 64 + b * 16 + lo;
            const int nb = p / S_;
            const int s = p - nb * S_;
            #pragma unroll
            for (int a = 0; a < 2; ++a) {
                const int d0 = wc * 32 + a * 16 + lg * 4;
                const float4v bs = *(const float4v*)(bias + o0 + d0);
                ushort4v pk;
                #pragma unroll
                for (int e = 0; e < 4; ++e) {
                    float vv = acc[a][b][e] + bs[e];
                    vv = vv > 0.f ? vv : 0.f;
                    pk[e] = f2bf(vv * osc);
                }
                *(ushort4v*)(outp + ((long)(head * N_ + nb) * S_ + s) * D_ + d0) = pk;
            }
        }
    } else {
        #pragma unroll
        for (int a = 0; a < 2; ++a) {
            const int d = wc * 32 + a * 16 + lo;
            const float bsc = bias[o0 + d];
            #pragma unroll
            for (int b = 0; b < 4; ++b) {
                const int pb = p0 + wr * 64 + b * 16 + lg * 4;
                const int nb = pb / S_;
                const int s0 = pb - nb * S_;
                ushort4v pk;
                #pragma unroll
                for (int e = 0; e < 4; ++e) {
                    float vv = acc[a][b][e] + bsc;
                    vv = vv > 0.f ? vv : 0.f;
                    pk[e] = f2bf(vv);
                }
                *(ushort4v*)(outp + ((long)(head * N_ + nb) * D_ + d) * S_ + s0) = pk;
            }
        }
    }
}

// ---------------------------------------------------------------------------
// Split-K(x4) flash attention, FIXED-MAX softmax (exact: scores >= 0 from
// ReLU'd Q,K; no overflow possible at this scale). Per tile: p = exp2(s+bias),
// l += sum(p) — no running max, no cross-lane reduce, no rescale branch.
// Partials are plain sums; combine just adds them.
// ---------------------------------------------------------------------------
__global__ __launch_bounds__(256) void attn_kernel(
    const ushort_t* __restrict__ Qh, const ushort_t* __restrict__ Kh,
    const ushort_t* __restrict__ Vt, const float* __restrict__ km,
    ushort_t* __restrict__ Pc, float* __restrict__ Lp)
{
    __shared__ char lds[16384 + 256];   // K 8KB | V 8KB | kms 256B

    const int tid = threadIdx.x;
    const int lane = tid & 63;
    const int w = tid >> 6;
    const int lg = lane >> 4;
    const int lo = lane & 15;

    const int split = blockIdx.y;               // 0..3
    const int t1 = 7 + split * 6;               // 7,13,19,25
    const int t0 = split ? (1 + split * 6) : 0; // 0,7,13,19

    const int fid = blockIdx.x;          // 0..799, XCD-aware decode
    const int x = fid & 7;
    const int j = fid >> 3;
    const int b = x + 8 * (j / 25);
    const int q0 = (j % 25) * 64;
    const int n = b & (N_ - 1);

    char* Kl = lds;
    char* Vl = lds + 8192;
    const float* kms = (const float*)(lds + 16384);
    const int wbase = (tid & 192) * 16;

    const int qrow = q0 + w * 16 + lo;
    const int qcl = qrow < S_ ? qrow : S_ - 1;
    const ushort_t* qp = Qh + ((long)b * S_ + qcl) * D_ + lg * 4;
    short8v qf[2];
    #pragma unroll
    for (int ks = 0; ks < 2; ++ks) {
        ((uint2*)&qf[ks])[0] = *(const uint2*)(qp + ks * 32);
        ((uint2*)&qf[ks])[1] = *(const uint2*)(qp + ks * 32 + 16);
    }

    float4v acc[4];
    #pragma unroll
    for (int dt = 0; dt < 4; ++dt) acc[dt] = (float4v){0.f, 0.f, 0.f, 0.f};
    float l_run = 0.f;                   // per-lane partial sum of weights

    auto stageK = [&](int kb) {
        #pragma unroll
        for (int i = 0; i < 2; ++i) {
            const int s = i * 256 + tid;
            const int row = s >> 3;
            const int c16 = (s & 7) ^ (row & 7);
            int krow = kb + row; if (krow >= S_) krow = S_ - 1;
            gload_lds16(Kh + ((long)b * S_ + krow) * D_ + c16 * 8,
                        Kl + i * 4096 + wbase);
        }
        if (w == 0)
            gload_lds4(km + (long)n * KMP_ + kb + lane, (void*)kms);
    };
    auto stageV = [&](int kb) {
        #pragma unroll
        for (int i = 0; i < 2; ++i) {
            const int s = i * 256 + tid;
            const int row = s >> 3;
            const int c16 = (s & 7) ^ (row & 7);
            int kc = kb + c16 * 8; if (kc > S_ - 8) kc = S_ - 8;
            gload_lds16(Vt + ((long)b * D_ + row) * S_ + kc,
                        Vl + i * 4096 + wbase);
        }
    };

    for (int t = t0; t < t1; ++t) {
        stageK(t * 64);
        stageV(t * 64);
        asm volatile("s_waitcnt vmcnt(2)" ::: "memory");
        __builtin_amdgcn_s_barrier();

        float4v s[4];
        __builtin_amdgcn_s_setprio(1);
        #pragma unroll
        for (int kt = 0; kt < 4; ++kt) {
            s[kt] = (float4v){0.f, 0.f, 0.f, 0.f};
            #pragma unroll
            for (int ks = 0; ks < 2; ++ks) {
                const int row = kt * 16 + lo;
                const int base = row * 128 + ks * 64 + lg * 8;
                const int swr = (row & 7) << 4;
                short8v kf;
                ((uint2*)&kf)[0] = *(const uint2*)(Kl + (base ^ swr));
                ((uint2*)&kf)[1] = *(const uint2*)(Kl + ((base + 32) ^ swr));
                s[kt] = mfma16(kf, qf[ks], s[kt]);
            }
        }
        __builtin_amdgcn_s_setprio(0);

        // ---- fixed-max softmax: p = exp2(s + bias); l accumulates ----
        float p[4][4];
        #pragma unroll
        for (int kt = 0; kt < 4; ++kt) {
            const float4v bv4 = *(const float4v*)&kms[kt * 16 + lg * 4];
            #pragma unroll
            for (int r = 0; r < 4; ++r)
                p[kt][r] = exp2_fast(s[kt][r] + bv4[r]);
        }
        float rs4[4];
        #pragma unroll
        for (int kt = 0; kt < 4; ++kt)
            rs4[kt] = (p[kt][0] + p[kt][1]) + (p[kt][2] + p[kt][3]);
        l_run += (rs4[0] + rs4[1]) + (rs4[2] + rs4[3]);

        short8v pf[2];
        #pragma unroll
        for (int kt = 0; kt < 4; ++kt) {
            const unsigned w0 = cvt_pk_bf16(p[kt][0], p[kt][1]);
            const unsigned w1 = cvt_pk_bf16(p[kt][2], p[kt][3]);
            ((unsigned*)&pf[kt >> 1])[(kt & 1) * 2] = w0;
            ((unsigned*)&pf[kt >> 1])[(kt & 1) * 2 + 1] = w1;
        }

        asm volatile("s_waitcnt vmcnt(0)" ::: "memory");
        __builtin_amdgcn_s_barrier();

        __builtin_amdgcn_s_setprio(1);
        #pragma unroll
        for (int dt = 0; dt < 4; ++dt) {
            #pragma unroll
            for (int ks = 0; ks < 2; ++ks) {
                const int row = dt * 16 + lo;
                const int base = row * 128 + ks * 64 + lg * 8;
                const int swr = (row & 7) << 4;
                short8v vf;
                ((uint2*)&vf)[0] = *(const uint2*)(Vl + (base ^ swr));
                ((uint2*)&vf)[1] = *(const uint2*)(Vl + ((base + 32) ^ swr));
                acc[dt] = mfma16(vf, pf[ks], acc[dt]);
            }
        }
        __builtin_amdgcn_s_setprio(0);
        __syncthreads();     // all reads done before next tile's DMAs
    }

    // final cross-lane l reduce (once per kernel)
    l_run += __shfl_xor(l_run, 16, 64);
    l_run += __shfl_xor(l_run, 32, 64);

    if (qrow < S_) {
        const long rbase = ((long)split * 32 + b) * S_ + qrow;
        if (lg == 0) Lp[rbase] = l_run;
        ushort_t* P = Pc + rbase * 64;
        #pragma unroll
        for (int dt = 0; dt < 4; ++dt) {
            uint2 uu;
            uu.x = cvt_pk_bf16(acc[dt][0], acc[dt][1]);
            uu.y = cvt_pk_bf16(acc[dt][2], acc[dt][3]);
            *(uint2*)(P + dt * 16 + lg * 4) = uu;
        }
    }
}

// ---------------------------------------------------------------------------
// Fused split-K combine (plain sums — fixed-max) + residual + full LayerNorm.
// ---------------------------------------------------------------------------
__global__ __launch_bounds__(256) void combine_ln_kernel(
    const ushort_t* __restrict__ Pc, const float* __restrict__ Lp,
    const float* __restrict__ qm, const ushort_t* __restrict__ qbf,
    const float* __restrict__ gamma, const float* __restrict__ beta,
    ushort_t* __restrict__ Om)
{
    const int tid = threadIdx.x;
    const int wv = tid >> 6, lane = tid & 63;
    const long pos = (long)blockIdx.x * 4 + wv;     // n*S + q
    const int n = (int)(pos / S_);
    const int q = (int)(pos - (long)n * S_);
    const int head = lane >> 3;
    const int d0 = (lane & 7) * 8;

    float L = 0.f;
    float o[8] = {0.f, 0.f, 0.f, 0.f, 0.f, 0.f, 0.f, 0.f};
    #pragma unroll
    for (int s = 0; s < 4; ++s) {
        const long rb = ((long)(s * 32 + head * 4 + n) * S_ + q);
        L += Lp[rb];
        const ushort4v a0 = *(const ushort4v*)(Pc + rb * 64 + d0);
        const ushort4v a1 = *(const ushort4v*)(Pc + rb * 64 + d0 + 4);
        #pragma unroll
        for (int e = 0; e < 4; ++e) {
            o[e] += bf2f(a0[e]);
            o[4 + e] += bf2f(a1[e]);
        }
    }
    L = fmaxf(L, 1e-20f);
    const float scale = qm[pos] / L;
    const short8v qv = *(const short8v*)(qbf + pos * C_ + lane * 8);
    float v8[8];
    float sum = 0.f, ssq = 0.f;
    #pragma unroll
    for (int e = 0; e < 8; ++e) {
        const float v = o[e] * scale + bf2f(((const ushort_t*)&qv)[e]);
        v8[e] = v;
        sum += v; ssq += v * v;
    }
    #pragma unroll
    for (int off = 32; off > 0; off >>= 1) {
        sum += __shfl_xor(sum, off, 64);
        ssq += __shfl_xor(ssq, off, 64);
    }
    const float mean = sum * (1.f / 512.f);
    float var = (ssq - sum * mean) * (1.f / 511.f);
    var = var > 0.f ? var : 0.f;
    const float inv = 1.f / (sqrtf(var) + EPS_);

    const float4v g0 = *(const float4v*)(gamma + lane * 8);
    const float4v g1 = *(const float4v*)(gamma + lane * 8 + 4);
    const float4v b0 = *(const float4v*)(beta + lane * 8);
    const float4v b1 = *(const float4v*)(beta + lane * 8 + 4);
    ushort4v ov0, ov1;
    #pragma unroll
    for (int e = 0; e < 4; ++e) {
        ov0[e] = f2bf(g0[e] * (v8[e] - mean) * inv + b0[e]);
        ov1[e] = f2bf(g1[e] * (v8[4 + e] - mean) * inv + b1[e]);
    }
    *(ushort4v*)(Om + pos * C_ + lane * 8) = ov0;
    *(ushort4v*)(Om + pos * C_ + lane * 8 + 4) = ov1;
}

// ---------------------------------------------------------------------------
// Output transpose: Om (bf16, [p][c], already LayerNormed) -> fp32 NTCHW.
// ---------------------------------------------------------------------------
__global__ __launch_bounds__(256) void ln_write_kernel(
    const ushort_t* __restrict__ Om, float* __restrict__ out)
{
    __shared__ float Tl[64][197];
    const int nt = blockIdx.x;
    const int ct = blockIdx.y;
    const int tid = threadIdx.x;

    const int c0 = (tid & 15) * 4;
    #pragma unroll
    for (int i = 0; i < 13; ++i) {
        const int idx = i * 256 + tid;
        if (idx < 3136) {
            const int hw = idx >> 4;
            const long p = (long)nt * HW_ + hw;
            const ushort4v ov = *(const ushort4v*)(Om + p * C_ + ct * 64 + c0);
            #pragma unroll
            for (int e = 0; e < 4; ++e) Tl[c0 + e][hw] = bf2f(ov[e]);
        }
    }
    __syncthreads();
    const long obase = ((long)nt * C_ + ct * 64) * HW_;
    #pragma unroll
    for (int i = 0; i < 13; ++i) {
        const int idx = i * 256 + tid;
        if (idx < 3136) {
            const int c = idx / 49;
            const int q4 = idx - c * 49;
            float4 v;
            v.x = Tl[c][q4 * 4 + 0];
            v.y = Tl[c][q4 * 4 + 1];
            v.z = Tl[c][q4 * 4 + 2];
            v.w = Tl[c][q4 * 4 + 3];
            *(float4*)(out + obase + c * HW_ + q4 * 4) = v;
        }
    }
}

extern "C" void kernel_launch(void* const* d_in, const int* in_sizes, int n_in,
                              void* d_out, int out_size, void* d_ws, size_t ws_size,
                              hipStream_t stream) {
    const float* q_in  = (const float*)d_in[0];
    const float* k_in  = (const float*)d_in[1];
    const float* v_in  = (const float*)d_in[2];
    const float* Wq    = (const float*)d_in[3];
    const float* bq    = (const float*)d_in[4];
    const float* Wk    = (const float*)d_in[5];
    const float* bk    = (const float*)d_in[6];
    const float* Wv    = (const float*)d_in[7];
    const float* bv    = (const float*)d_in[8];
    const float* gamma = (const float*)d_in[9];
    const float* beta  = (const float*)d_in[10];
    float* out = (float*)d_out;

    const size_t PC = (size_t)P_TOT * C_;            // 3,211,264
    ushort_t* qbf = (ushort_t*)d_ws;
    ushort_t* kbf = qbf + PC;
    ushort_t* vbf = kbf + PC;
    ushort_t* Wbf = vbf + PC;                        // 3 x 512 x 512 bf16
    ushort_t* Qh  = Wbf + 3 * (size_t)C_ * C_;
    ushort_t* Kh  = Qh + PC;
    ushort_t* Vt  = Kh + PC;
    ushort_t* Om  = Vt + PC;                         // bf16 (final LN'd values)
    ushort_t* Pc  = Om + PC;                         // 4*32*1568*64 bf16
    float* Lp    = (float*)(Pc + 4L * 32 * S_ * 64); // 4*32*1568
    float* qm    = Lp + 4L * 32 * S_;
    float* km    = qm + P_TOT;                       // padded [4][1600]

    transpose_kernel<<<dim3(32, 8, 4), 256, 0, stream>>>(
        q_in, k_in, v_in, qbf, kbf, vbf, Wq, Wk, Wv, Wbf);
    mask_kernel<<<P_TOT / 4, 256, 0, stream>>>(qbf, kbf, qm, km);
    proj_all<<<1176, 256, 0, stream>>>(qbf, kbf, vbf, Wbf, bq, bk, bv, Qh, Kh, Vt);
    attn_kernel<<<dim3(800, 4), 256, 0, stream>>>(Qh, Kh, Vt, km, Pc, Lp);
    combine_ln_kernel<<<P_TOT / 4, 256, 0, stream>>>(Pc, Lp, qm, qbf, gamma, beta, Om);
    ln_write_kernel<<<dim3(32, 8), 256, 0, stream>>>(Om, out);
}